// Round 8
// baseline (588.030 us; speedup 1.0000x reference)
//
#include <hip/hip_runtime.h>
#include <math.h>

// ---------------------------------------------------------------------------
// Static geometry: N_ATOMS=200000, MAX_DEG=6, NAF=75, BATCH=1024, N_TASKS=12
// DEG_COUNTS = [2000, 40000, 60000, 58000, 38000, 1500, 500]
// ---------------------------------------------------------------------------
constexpr int OFFS[8] = {0, 2000, 42000, 102000, 160000, 198000, 199500, 200000};
constexpr int CNT[7]  = {2000, 40000, 60000, 58000, 38000, 1500, 500};
// conv tiles (64 atoms): {32, 625, 938, 907, 594, 24, 8} cumsum:
constexpr int C_OFF[8] = {0, 32, 657, 1595, 2502, 3096, 3120, 3128};
// pool tiles (8 atoms): {250, 5000, 7500, 7250, 4750, 188, 63} cumsum:
constexpr int P_OFF[8] = {0, 250, 5250, 12750, 20000, 24750, 24938, 25001};
#define BN_SCALE_C 0.9999950000374997f  // 1/sqrt(1+1e-5)

struct Adjs { const int* a[6]; };

typedef __attribute__((ext_vector_type(8))) short bf16x8;
typedef __attribute__((ext_vector_type(4))) float f32x4;

// split fp32 -> bf16 hi (exact truncation) + bf16 lo (truncated remainder)
__device__ __forceinline__ void split1(float x, ushort& h, ushort& l) {
    const unsigned u = __float_as_uint(x);
    h = (ushort)(u >> 16);
    const float r = x - __uint_as_float(u & 0xffff0000u);
    l = (ushort)(__float_as_uint(r) >> 16);
}

// ---------------------------------------------------------------------------
// Weight conversion -> per-lane MFMA fragment layout:
//   Wfrag[s][g][ks][lane][i] ushort; col = g*16 + (lane&15),
//   k = ks*32 + (lane>>4)*8 + i. Every B load = coalesced 1KB dwordx4.
// conv1: s=0..12, K=128 (KS=4).  conv0: d=0..6, K=160 zero-padded (KS=5).
// ---------------------------------------------------------------------------
__global__ __launch_bounds__(256)
void w1_convert_kernel(const float* __restrict__ W, ushort* __restrict__ hi,
                       ushort* __restrict__ lo) {
    const int t = blockIdx.x * 256 + threadIdx.x;
    if (t >= 13 * 8 * 4 * 64 * 8) return;
    const int i = t & 7, l = (t >> 3) & 63, ks = (t >> 9) & 3,
              g = (t >> 11) & 7, s = t >> 14;
    const int col = g * 16 + (l & 15);
    const int k = ks * 32 + (l >> 4) * 8 + i;
    ushort h, lw;
    split1(W[(size_t)(s * 128 + k) * 128 + col], h, lw);
    hi[t] = h; lo[t] = lw;
}

__global__ __launch_bounds__(256)
void w0_convert_kernel(const float* __restrict__ W, ushort* __restrict__ hi,
                       ushort* __restrict__ lo) {
    const int t = blockIdx.x * 256 + threadIdx.x;
    if (t >= 7 * 8 * 5 * 64 * 8) return;
    const int i = t & 7;
    const int r = t >> 3;
    const int l = r & 63;
    const int r2 = r >> 6;
    const int ks = r2 % 5;
    const int r3 = r2 / 5;
    const int g = r3 & 7, d = r3 >> 3;
    const int col = g * 16 + (l & 15);
    const int k = ks * 32 + (l >> 4) * 8 + i;
    float v = 0.f;
    if (d == 0) {
        if (k < 75) v = W[(size_t)(12 * 75 + k) * 128 + col];
    } else {
        if (k < 75)       v = W[(size_t)((2 * d - 2) * 75 + k) * 128 + col];
        else if (k < 150) v = W[(size_t)((2 * d - 1) * 75 + (k - 75)) * 128 + col];
    }
    ushort h, lw;
    split1(v, h, lw);
    hi[t] = h; lo[t] = lw;
}

// ---------------------------------------------------------------------------
// MFMA GEMM core: block = 64 atoms x 128 cols, 4 waves; wave w owns atoms
// [16w,16w+16). acc[g] = 16x16 D tile for cols [16g,16g+16).
// A fragments preloaded from LDS; B fragments streamed through a depth-4
// register pipeline, g-fastest order (independent acc chains between uses).
// ---------------------------------------------------------------------------
template<int KSTEPS, int SROW>
__device__ __forceinline__ void mfma_gemm(const ushort* sa_hi, const ushort* sa_lo,
                                          const ushort* wp_hi, const ushort* wp_lo,
                                          f32x4 acc[8], int l, int w)
{
    const int lr = l & 15, lq = l >> 4;
    const size_t lb = (size_t)l * 8;
    // preload all A fragments (LDS, low latency)
    bf16x8 ah[KSTEPS], al[KSTEPS];
    #pragma unroll
    for (int ks = 0; ks < KSTEPS; ++ks) {
        const int kb = ks * 32 + lq * 8;
        ah[ks] = *(const bf16x8*)(sa_hi + (size_t)(w * 16 + lr) * SROW + kb);
        al[ks] = *(const bf16x8*)(sa_lo + (size_t)(w * 16 + lr) * SROW + kb);
    }
    constexpr int NF = KSTEPS * 8;
    constexpr int DEPTH = 4;
    bf16x8 bh[DEPTH], bl[DEPTH];
    #pragma unroll
    for (int f = 0; f < DEPTH; ++f) {
        const int g = f & 7, ks = f >> 3;
        const size_t off = (size_t)(g * KSTEPS + ks) * 512 + lb;
        bh[f] = *(const bf16x8*)(wp_hi + off);
        bl[f] = *(const bf16x8*)(wp_lo + off);
    }
    #pragma unroll
    for (int f = 0; f < NF; ++f) {
        const int g = f & 7, ks = f >> 3;
        const int slot = f & (DEPTH - 1);
        const bf16x8 curh = bh[slot], curl = bl[slot];
        if (f + DEPTH < NF) {
            const int fn = f + DEPTH;
            const int gn = fn & 7, ksn = fn >> 3;
            const size_t off = (size_t)(gn * KSTEPS + ksn) * 512 + lb;
            bh[slot] = *(const bf16x8*)(wp_hi + off);
            bl[slot] = *(const bf16x8*)(wp_lo + off);
        }
        acc[g] = __builtin_amdgcn_mfma_f32_16x16x32_bf16(ah[ks], curh, acc[g], 0, 0, 0);
        acc[g] = __builtin_amdgcn_mfma_f32_16x16x32_bf16(al[ks], curh, acc[g], 0, 0, 0);
        acc[g] = __builtin_amdgcn_mfma_f32_16x16x32_bf16(ah[ks], curl, acc[g], 0, 0, 0);
    }
}

// ---------------------------------------------------------------------------
// Epilogue: acc -> LDS (fs[64][132] f32, re-using dead A planes) -> bias/relu/
// bn applied on coalesced float4 row writes (full 512B rows; no partial lines).
// D layout: col = g*16 + (lane&15), row = w*16 + (lane>>4)*4 + r  [m89]
// ---------------------------------------------------------------------------
__device__ __forceinline__ void mfma_epilogue(f32x4 acc[8], float* fs,
                                              const float* s_eb, float* out,
                                              int a0, int nat, int tid)
{
    const int l = tid & 63, w = tid >> 6, lr = l & 15, lq = l >> 4;
    __syncthreads();   // all waves done reading A planes
    #pragma unroll
    for (int g = 0; g < 8; ++g)
        #pragma unroll
        for (int r = 0; r < 4; ++r)
            fs[(size_t)(w * 16 + lq * 4 + r) * 132 + g * 16 + lr] = acc[g][r];
    __syncthreads();
    #pragma unroll
    for (int p = 0; p < 8; ++p) {
        const int row = p * 8 + (tid >> 5);
        if (row < nat) {
            const int c = (tid & 31) * 4;
            const float4 v  = *(const float4*)&fs[(size_t)row * 132 + c];
            const float4 bb = *(const float4*)&s_eb[c];
            const float4 gs = *(const float4*)&s_eb[128 + c];
            const float4 be = *(const float4*)&s_eb[256 + c];
            float4 o;
            o.x = fmaxf(v.x + bb.x, 0.f) * gs.x + be.x;
            o.y = fmaxf(v.y + bb.y, 0.f) * gs.y + be.y;
            o.z = fmaxf(v.z + bb.z, 0.f) * gs.z + be.z;
            o.w = fmaxf(v.w + bb.w, 0.f) * gs.w + be.w;
            *(float4*)(out + (size_t)(a0 + row) * 128 + c) = o;
        }
    }
}

// ---------------------------------------------------------------------------
// conv0 (MFMA): x[.][75] -> out[.][128]. A = [nbr-sum | self | 0pad], K=160.
// ---------------------------------------------------------------------------
template<int D>
__device__ __forceinline__ void conv0_body(int tile, const float* __restrict__ x,
    const ushort* __restrict__ wp_hi, const ushort* __restrict__ wp_lo,
    const float* __restrict__ b, const float* __restrict__ gamma,
    const float* __restrict__ beta, const int* __restrict__ adjp,
    float* __restrict__ out, ushort* s_ahi, ushort* s_alo, int* s_adj,
    float* s_eb, int tid)
{
    constexpr int SROW = 168;   // 160 + 8 pad (ushorts)
    const int a0 = OFFS[D] + tile * 64;
    const int nat = min(64, OFFS[D + 1] - a0);

    if (tid < 128) {
        float bb;
        if constexpr (D > 0)
            bb = b[(2 * D - 2) * 128 + tid] + b[(2 * D - 1) * 128 + tid];
        else
            bb = b[12 * 128 + tid];
        s_eb[tid] = bb;
        s_eb[128 + tid] = gamma[tid] * BN_SCALE_C;
        s_eb[256 + tid] = beta[tid];
    }
    if constexpr (D > 0) {
        for (int e = tid; e < 64 * D; e += 256) {
            const int al = e / D;
            if (al < nat)
                s_adj[e] = adjp[(size_t)(a0 - OFFS[D] + al) * D + (e - al * D)];
        }
        __syncthreads();
    }
    // zero the pad region (all 64 rows)
    if constexpr (D == 0) {
        for (int e = tid; e < 64 * 85; e += 256) {
            const int al = e / 85, k = 75 + e - (e / 85) * 85;
            s_ahi[al * SROW + k] = 0; s_alo[al * SROW + k] = 0;
        }
    } else {
        for (int e = tid; e < 64 * 10; e += 256) {
            const int al = e / 10, k = 150 + e - (e / 10) * 10;
            s_ahi[al * SROW + k] = 0; s_alo[al * SROW + k] = 0;
        }
    }
    // stage [nbr-sum | self]
    #pragma unroll 4
    for (int p = 0; p < 19; ++p) {
        const int e = p * 256 + tid;
        if (e < 4800) {
            const int al = e / 75;
            const int kk = e - al * 75;
            if (al < nat) {
                const float self = x[(size_t)(a0 + al) * 75 + kk];
                ushort h, l;
                if constexpr (D > 0) {
                    float sum = 0.f;
                    #pragma unroll
                    for (int i = 0; i < D; ++i)
                        sum += x[(size_t)s_adj[al * D + i] * 75 + kk];
                    split1(sum, h, l);
                    s_ahi[al * SROW + kk] = h; s_alo[al * SROW + kk] = l;
                    split1(self, h, l);
                    s_ahi[al * SROW + 75 + kk] = h; s_alo[al * SROW + 75 + kk] = l;
                } else {
                    split1(self, h, l);
                    s_ahi[al * SROW + kk] = h; s_alo[al * SROW + kk] = l;
                }
            }
        }
    }
    __syncthreads();

    const int l = tid & 63, w = tid >> 6;
    f32x4 acc[8];
    #pragma unroll
    for (int g = 0; g < 8; ++g) acc[g] = (f32x4){0.f, 0.f, 0.f, 0.f};
    mfma_gemm<5, SROW>(s_ahi, s_alo, wp_hi + (size_t)D * 20480,
                       wp_lo + (size_t)D * 20480, acc, l, w);
    mfma_epilogue(acc, (float*)s_ahi, s_eb, out, a0, nat, tid);
}

__global__ __launch_bounds__(256, 3)
void conv0_merged(const float* __restrict__ x, const ushort* __restrict__ wp_hi,
                  const ushort* __restrict__ wp_lo, const float* __restrict__ b,
                  const float* __restrict__ gamma, const float* __restrict__ beta,
                  Adjs adj, float* __restrict__ out)
{
    __shared__ ushort s_a[2][64 * 168];   // hi, lo; aliased as fs[64][132] f32
    __shared__ int s_adj[64 * 6];
    __shared__ float s_eb[384];
    const int blk = blockIdx.x, tid = threadIdx.x;
    #define C0(D) conv0_body<D>(blk - C_OFF[D], x, wp_hi, wp_lo, b, gamma, beta, \
        (D > 0) ? adj.a[D - 1] : nullptr, out, s_a[0], s_a[1], s_adj, s_eb, tid)
    if      (blk < C_OFF[1]) C0(0);
    else if (blk < C_OFF[2]) C0(1);
    else if (blk < C_OFF[3]) C0(2);
    else if (blk < C_OFF[4]) C0(3);
    else if (blk < C_OFF[5]) C0(4);
    else if (blk < C_OFF[6]) C0(5);
    else                     C0(6);
    #undef C0
}

// ---------------------------------------------------------------------------
// conv1 (MFMA): x[.][128] -> out[.][128]; two K=128 phases share LDS tile.
// ---------------------------------------------------------------------------
template<int D, bool PHASE0>
__device__ __forceinline__ void conv1_stage(const float* __restrict__ x,
    ushort* s_ahi, ushort* s_alo, const int* s_adj, int a0, int nat, int tid)
{
    constexpr int SROW = 136;
    #pragma unroll 4
    for (int p = 0; p < 8; ++p) {
        const int e = p * 256 + tid;
        const int al = e >> 5, c = e & 31;
        if (al < nat) {
            float4 v;
            if (PHASE0 && D > 0) {
                v = make_float4(0.f, 0.f, 0.f, 0.f);
                #pragma unroll
                for (int i = 0; i < D; ++i) {
                    const float4 t = *((const float4*)(x + (size_t)s_adj[al * D + i] * 128) + c);
                    v.x += t.x; v.y += t.y; v.z += t.z; v.w += t.w;
                }
            } else {
                v = *((const float4*)(x + (size_t)(a0 + al) * 128) + c);
            }
            ushort4 h, lo;
            split1(v.x, h.x, lo.x); split1(v.y, h.y, lo.y);
            split1(v.z, h.z, lo.z); split1(v.w, h.w, lo.w);
            *(ushort4*)&s_ahi[al * SROW + c * 4] = h;
            *(ushort4*)&s_alo[al * SROW + c * 4] = lo;
        }
    }
}

template<int D>
__device__ __forceinline__ void conv1_body(int tile, const float* __restrict__ x,
    const ushort* __restrict__ wp_hi, const ushort* __restrict__ wp_lo,
    const float* __restrict__ b, const float* __restrict__ gamma,
    const float* __restrict__ beta, const int* __restrict__ adjp,
    float* __restrict__ out, ushort* s_ahi, ushort* s_alo, int* s_adj,
    float* s_eb, int tid)
{
    constexpr int SROW = 136;
    const int a0 = OFFS[D] + tile * 64;
    const int nat = min(64, OFFS[D + 1] - a0);

    if (tid < 128) {
        float bb;
        if constexpr (D > 0)
            bb = b[(2 * D - 2) * 128 + tid] + b[(2 * D - 1) * 128 + tid];
        else
            bb = b[12 * 128 + tid];
        s_eb[tid] = bb;
        s_eb[128 + tid] = gamma[tid] * BN_SCALE_C;
        s_eb[256 + tid] = beta[tid];
    }
    if constexpr (D > 0) {
        for (int e = tid; e < 64 * D; e += 256) {
            const int al = e / D;
            if (al < nat)
                s_adj[e] = adjp[(size_t)(a0 - OFFS[D] + al) * D + (e - al * D)];
        }
        __syncthreads();
    }

    const int l = tid & 63, w = tid >> 6;
    f32x4 acc[8];
    #pragma unroll
    for (int g = 0; g < 8; ++g) acc[g] = (f32x4){0.f, 0.f, 0.f, 0.f};

    conv1_stage<D, true>(x, s_ahi, s_alo, s_adj, a0, nat, tid);
    __syncthreads();
    {
        const size_t wb = (size_t)((D == 0) ? 12 : (2 * D - 2)) * 16384;
        mfma_gemm<4, SROW>(s_ahi, s_alo, wp_hi + wb, wp_lo + wb, acc, l, w);
    }
    if constexpr (D > 0) {
        __syncthreads();
        conv1_stage<D, false>(x, s_ahi, s_alo, s_adj, a0, nat, tid);
        __syncthreads();
        const size_t wb = (size_t)(2 * D - 1) * 16384;
        mfma_gemm<4, SROW>(s_ahi, s_alo, wp_hi + wb, wp_lo + wb, acc, l, w);
    }
    mfma_epilogue(acc, (float*)s_ahi, s_eb, out, a0, nat, tid);
}

__global__ __launch_bounds__(256, 4)
void conv1_merged(const float* __restrict__ x, const ushort* __restrict__ wp_hi,
                  const ushort* __restrict__ wp_lo, const float* __restrict__ b,
                  const float* __restrict__ gamma, const float* __restrict__ beta,
                  Adjs adj, float* __restrict__ out)
{
    __shared__ ushort s_a[2][64 * 136];   // hi, lo; aliased as fs[64][132] f32
    __shared__ int s_adj[64 * 6];
    __shared__ float s_eb[384];
    const int blk = blockIdx.x, tid = threadIdx.x;
    #define C1(D) conv1_body<D>(blk - C_OFF[D], x, wp_hi, wp_lo, b, gamma, beta, \
        (D > 0) ? adj.a[D - 1] : nullptr, out, s_a[0], s_a[1], s_adj, s_eb, tid)
    if      (blk < C_OFF[1]) C1(0);
    else if (blk < C_OFF[2]) C1(1);
    else if (blk < C_OFF[3]) C1(2);
    else if (blk < C_OFF[4]) C1(3);
    else if (blk < C_OFF[5]) C1(4);
    else if (blk < C_OFF[6]) C1(5);
    else                     C1(6);
    #undef C1
}

// ---------------------------------------------------------------------------
// pool: out[a] = max(self, neighbors), 128 feats.
// ---------------------------------------------------------------------------
template<int D>
__device__ __forceinline__ void pool_body(int tile, const float* __restrict__ x,
    const int* __restrict__ adjp, float* __restrict__ out, int tid)
{
    const int tx = tid & 31;
    const int ai = tile * 8 + (tid >> 5);
    if (ai >= CNT[D]) return;
    const int a = OFFS[D] + ai;
    float4 v = *((const float4*)(x + (size_t)a * 128) + tx);
    if constexpr (D > 0) {
        #pragma unroll
        for (int i = 0; i < D; ++i) {
            const int n = adjp[(size_t)ai * D + i];
            const float4 t = *((const float4*)(x + (size_t)n * 128) + tx);
            v.x = fmaxf(v.x, t.x); v.y = fmaxf(v.y, t.y);
            v.z = fmaxf(v.z, t.z); v.w = fmaxf(v.w, t.w);
        }
    }
    *((float4*)(out + (size_t)a * 128) + tx) = v;
}

__global__ __launch_bounds__(256)
void pool_merged(const float* __restrict__ x, Adjs adj, float* __restrict__ out)
{
    const int blk = blockIdx.x, tid = threadIdx.x;
    #define PB(D) pool_body<D>(blk - P_OFF[D], x, (D > 0) ? adj.a[D - 1] : nullptr, out, tid)
    if      (blk < P_OFF[1]) PB(0);
    else if (blk < P_OFF[2]) PB(1);
    else if (blk < P_OFF[3]) PB(2);
    else if (blk < P_OFF[4]) PB(3);
    else if (blk < P_OFF[5]) PB(4);
    else if (blk < P_OFF[6]) PB(5);
    else                     PB(6);
    #undef PB
}

// ---------------------------------------------------------------------------
// dense0 with fused pool2, per-degree tiles: stage pooled rows in LDS,
// W[128][64] streamed from global (L1-resident) -> 4 blocks/CU.
// y = bn2(relu(pool(x) @ W + b)) -> out[200000][64]
// ---------------------------------------------------------------------------
template<int D>
__device__ __forceinline__ void d0_body(int tile, const float* __restrict__ x,
    const float* __restrict__ W, const float* __restrict__ b,
    const float* __restrict__ gamma, const float* __restrict__ beta,
    const int* __restrict__ adjp, float* __restrict__ out,
    float* s_a /*64*132*/, int* s_adj, int tid)
{
    const int a0 = OFFS[D] + tile * 64;
    const int nat = min(64, OFFS[D + 1] - a0);

    if constexpr (D > 0) {
        for (int e = tid; e < 64 * D; e += 256) {
            const int al = e / D;
            if (al < nat)
                s_adj[e] = adjp[(size_t)(a0 - OFFS[D] + al) * D + (e - al * D)];
        }
        __syncthreads();
    }
    {   // stage pooled rows: 8 atoms/pass, 32 lanes (float4) each
        const int tx4 = tid & 31, ag = tid >> 5;
        #pragma unroll
        for (int ap = 0; ap < 8; ++ap) {
            const int al = ap * 8 + ag;
            if (al < nat) {
                float4 v = *((const float4*)(x + (size_t)(a0 + al) * 128) + tx4);
                if constexpr (D > 0) {
                    #pragma unroll
                    for (int i = 0; i < D; ++i) {
                        const float4 t =
                            *((const float4*)(x + (size_t)s_adj[al * D + i] * 128) + tx4);
                        v.x = fmaxf(v.x, t.x); v.y = fmaxf(v.y, t.y);
                        v.z = fmaxf(v.z, t.z); v.w = fmaxf(v.w, t.w);
                    }
                }
                *(float4*)&s_a[al * 132 + tx4 * 4] = v;
            }
        }
    }
    __syncthreads();

    const int tx = tid & 15, ty = tid >> 4;
    float acc[4][4];
    #pragma unroll
    for (int i = 0; i < 4; ++i)
        #pragma unroll
        for (int j = 0; j < 4; ++j) acc[i][j] = 0.f;

    // K in steps of 4: float4 A reads (ds_read_b128), W from global (L1)
    #pragma unroll 4
    for (int k4 = 0; k4 < 32; ++k4) {
        float4 wk[4];
        #pragma unroll
        for (int kk = 0; kk < 4; ++kk)
            wk[kk] = *(const float4*)(W + (size_t)(k4 * 4 + kk) * 64 + tx * 4);
        #pragma unroll
        for (int i = 0; i < 4; ++i) {
            const float4 av = *(const float4*)&s_a[(ty * 4 + i) * 132 + k4 * 4];
            acc[i][0] = fmaf(av.x, wk[0].x, acc[i][0]);
            acc[i][1] = fmaf(av.x, wk[0].y, acc[i][1]);
            acc[i][2] = fmaf(av.x, wk[0].z, acc[i][2]);
            acc[i][3] = fmaf(av.x, wk[0].w, acc[i][3]);
            acc[i][0] = fmaf(av.y, wk[1].x, acc[i][0]);
            acc[i][1] = fmaf(av.y, wk[1].y, acc[i][1]);
            acc[i][2] = fmaf(av.y, wk[1].z, acc[i][2]);
            acc[i][3] = fmaf(av.y, wk[1].w, acc[i][3]);
            acc[i][0] = fmaf(av.z, wk[2].x, acc[i][0]);
            acc[i][1] = fmaf(av.z, wk[2].y, acc[i][1]);
            acc[i][2] = fmaf(av.z, wk[2].z, acc[i][2]);
            acc[i][3] = fmaf(av.z, wk[2].w, acc[i][3]);
            acc[i][0] = fmaf(av.w, wk[3].x, acc[i][0]);
            acc[i][1] = fmaf(av.w, wk[3].y, acc[i][1]);
            acc[i][2] = fmaf(av.w, wk[3].z, acc[i][2]);
            acc[i][3] = fmaf(av.w, wk[3].w, acc[i][3]);
        }
    }
    const int j = tx * 4;
    float bb[4], gs[4], be[4];
    #pragma unroll
    for (int c = 0; c < 4; ++c) {
        bb[c] = b[j + c]; gs[c] = gamma[j + c] * BN_SCALE_C; be[c] = beta[j + c];
    }
    #pragma unroll
    for (int i = 0; i < 4; ++i) {
        const int al = ty * 4 + i;
        if (al < nat) {
            float4 o;
            o.x = fmaxf(acc[i][0] + bb[0], 0.f) * gs[0] + be[0];
            o.y = fmaxf(acc[i][1] + bb[1], 0.f) * gs[1] + be[1];
            o.z = fmaxf(acc[i][2] + bb[2], 0.f) * gs[2] + be[2];
            o.w = fmaxf(acc[i][3] + bb[3], 0.f) * gs[3] + be[3];
            *(float4*)(out + (size_t)(a0 + al) * 64 + j) = o;
        }
    }
}

__global__ __launch_bounds__(256, 4)
void dense0_pool_merged(const float* __restrict__ x, const float* __restrict__ W,
                        const float* __restrict__ b, const float* __restrict__ gamma,
                        const float* __restrict__ beta, Adjs adj,
                        float* __restrict__ out)
{
    __shared__ float s_a[64 * 132];
    __shared__ int s_adj[64 * 6];
    const int blk = blockIdx.x, tid = threadIdx.x;
    #define D0(D) d0_body<D>(blk - C_OFF[D], x, W, b, gamma, beta, \
        (D > 0) ? adj.a[D - 1] : nullptr, out, s_a, s_adj, tid)
    if      (blk < C_OFF[1]) D0(0);
    else if (blk < C_OFF[2]) D0(1);
    else if (blk < C_OFF[3]) D0(2);
    else if (blk < C_OFF[4]) D0(3);
    else if (blk < C_OFF[5]) D0(4);
    else if (blk < C_OFF[6]) D0(5);
    else                     D0(6);
    #undef D0
}

// ---------------------------------------------------------------------------
// bucketing: counts -> scan -> scatter
// ---------------------------------------------------------------------------
__global__ void zero_counts_kernel(int* __restrict__ counts) {
    counts[blockIdx.x * 256 + threadIdx.x] = 0;   // grid 4
}

__global__ __launch_bounds__(256)
void hist_kernel(const int* __restrict__ mem, int* __restrict__ counts) {
    const int a = blockIdx.x * 256 + threadIdx.x;
    if (a < 200000) atomicAdd(&counts[mem[a]], 1);
}

__global__ __launch_bounds__(1024)
void scan_kernel(const int* __restrict__ counts, int* __restrict__ starts,
                 int* __restrict__ cursor) {
    __shared__ int s[1024];
    const int tid = threadIdx.x;
    s[tid] = counts[tid];
    __syncthreads();
    #pragma unroll
    for (int off = 1; off < 1024; off <<= 1) {
        const int v = (tid >= off) ? s[tid - off] : 0;
        __syncthreads();
        s[tid] += v;
        __syncthreads();
    }
    const int st = (tid == 0) ? 0 : s[tid - 1];
    starts[tid] = st;
    cursor[tid] = st;
    if (tid == 1023) starts[1024] = s[1023];
}

__global__ __launch_bounds__(256)
void scatter_kernel(const int* __restrict__ mem, int* __restrict__ cursor,
                    int* __restrict__ idx) {
    const int a = blockIdx.x * 256 + threadIdx.x;
    if (a < 200000) {
        const int p = atomicAdd(&cursor[mem[a]], 1);
        idx[p] = a;
    }
}

// ---------------------------------------------------------------------------
// per-segment fused dense1 + reduce: block = segment.
// ---------------------------------------------------------------------------
__global__ __launch_bounds__(256, 4)
void seg_dense1_kernel(const float* __restrict__ y0, const float* __restrict__ W,
                       const float* __restrict__ b, const float* __restrict__ gamma,
                       const float* __restrict__ beta, const int* __restrict__ idx,
                       const int* __restrict__ starts, float* __restrict__ accum)
{
    __shared__ float s_a[64][68];
    __shared__ float s_w[64][64];
    __shared__ float s_red[16][64];
    const int tid = threadIdx.x;
    const int seg = blockIdx.x;
    const int s0 = starts[seg];
    const int cnt = starts[seg + 1] - s0;

    #pragma unroll
    for (int p = 0; p < 4; ++p) {
        const int f = p * 256 + tid;
        const int r = f >> 4, c = (f & 15) * 4;
        *(float4*)&s_w[r][c] = *(const float4*)(W + r * 64 + c);
    }

    const int tx = tid & 15, ty = tid >> 4;
    const int j = tx * 4;
    float bb[4], gs[4], be[4];
    #pragma unroll
    for (int c = 0; c < 4; ++c) {
        bb[c] = b[j + c]; gs[c] = gamma[j + c] * BN_SCALE_C; be[c] = beta[j + c];
    }
    float facc[4] = {0.f, 0.f, 0.f, 0.f};

    for (int t0 = 0; t0 < cnt; t0 += 64) {
        const int nt = min(64, cnt - t0);
        __syncthreads();
        #pragma unroll
        for (int p = 0; p < 4; ++p) {
            const int e = p * 256 + tid;
            const int al = e >> 4, c = e & 15;
            if (al < nt) {
                const int a = idx[s0 + t0 + al];
                *(float4*)&s_a[al][c * 4] = *((const float4*)(y0 + (size_t)a * 64) + c);
            }
        }
        __syncthreads();
        float acc[4][4];
        #pragma unroll
        for (int i = 0; i < 4; ++i)
            #pragma unroll
            for (int c = 0; c < 4; ++c) acc[i][c] = 0.f;
        #pragma unroll 8
        for (int k = 0; k < 64; ++k) {
            const float4 w = *(float4*)&s_w[k][tx * 4];
            #pragma unroll
            for (int i = 0; i < 4; ++i) {
                const float av = s_a[ty * 4 + i][k];
                acc[i][0] = fmaf(av, w.x, acc[i][0]);
                acc[i][1] = fmaf(av, w.y, acc[i][1]);
                acc[i][2] = fmaf(av, w.z, acc[i][2]);
                acc[i][3] = fmaf(av, w.w, acc[i][3]);
            }
        }
        #pragma unroll
        for (int i = 0; i < 4; ++i) {
            if (ty * 4 + i < nt) {
                #pragma unroll
                for (int c = 0; c < 4; ++c)
                    facc[c] += fmaxf(acc[i][c] + bb[c], 0.f) * gs[c] + be[c];
            }
        }
    }
    __syncthreads();
    #pragma unroll
    for (int c = 0; c < 4; ++c) s_red[ty][j + c] = facc[c];
    __syncthreads();
    if (tid < 64) {
        float s = 0.f;
        #pragma unroll
        for (int q = 0; q < 16; ++q) s += s_red[q][tid];
        accum[(size_t)seg * 64 + tid] = s;
    }
}

// ---------------------------------------------------------------------------
// final: fp = tanh(accum); heads.
// d_out: out[12288] var[12288] out[12288] log_var[12288] fp[65536]
// ---------------------------------------------------------------------------
__global__ __launch_bounds__(256)
void final_kernel(const float* __restrict__ accum,
                  const float* __restrict__ regW, const float* __restrict__ regb,
                  const float* __restrict__ uncW, const float* __restrict__ uncb,
                  float* __restrict__ out)
{
    __shared__ float s_f[256];
    const int tid = threadIdx.x;
    const int rl = tid >> 6;
    const int c = tid & 63;
    const int r = blockIdx.x * 4 + rl;
    const float f = tanhf(accum[(size_t)r * 64 + c]);
    out[49152 + (size_t)r * 64 + c] = f;
    s_f[tid] = f;
    __syncthreads();
    if (c < 24) {
        const bool isreg = (c < 12);
        const int t = isreg ? c : c - 12;
        const float* Wm = isreg ? regW : uncW;
        float a = isreg ? regb[t] : uncb[t];
        #pragma unroll 8
        for (int k = 0; k < 64; ++k)
            a = fmaf(s_f[rl * 64 + k], Wm[k * 12 + t], a);
        if (isreg) {
            out[(size_t)r * 12 + t] = a;
            out[24576 + (size_t)r * 12 + t] = a;
        } else {
            out[36864 + (size_t)r * 12 + t] = a;
            out[12288 + (size_t)r * 12 + t] = expf(a);
        }
    }
}

// ---------------------------------------------------------------------------
extern "C" void kernel_launch(void* const* d_in, const int* in_sizes, int n_in,
                              void* d_out, int out_size, void* d_ws, size_t ws_size,
                              hipStream_t stream)
{
    const float* atom_features = (const float*)d_in[0];
    const int*   membership    = (const int*)d_in[2];
    Adjs adj;
    for (int d = 1; d <= 6; ++d) adj.a[d - 1] = (const int*)d_in[3 + d];
    const float* conv0_W = (const float*)d_in[10];
    const float* conv0_b = (const float*)d_in[11];
    const float* conv1_W = (const float*)d_in[12];
    const float* conv1_b = (const float*)d_in[13];
    const float* bn0_g = (const float*)d_in[14];
    const float* bn0_b = (const float*)d_in[15];
    const float* bn1_g = (const float*)d_in[16];
    const float* bn1_b = (const float*)d_in[17];
    const float* bn2_g = (const float*)d_in[18];
    const float* bn2_b = (const float*)d_in[19];
    const float* bn3_g = (const float*)d_in[20];
    const float* bn3_b = (const float*)d_in[21];
    const float* dense0_W = (const float*)d_in[22];
    const float* dense0_b = (const float*)d_in[23];
    const float* dense1_W = (const float*)d_in[24];
    const float* dense1_b = (const float*)d_in[25];
    const float* reg_W = (const float*)d_in[26];
    const float* reg_b = (const float*)d_in[27];
    const float* unc_W = (const float*)d_in[28];
    const float* unc_b = (const float*)d_in[29];

    float* ws    = (float*)d_ws;
    float* buf0  = ws;                         // 200000*128
    float* buf1  = ws + 25600000;              // 200000*128
    float* accum = ws + 51200000;              // 1024*64
    int*   idx     = (int*)(ws + 51265536);    // 200000
    int*   counts  = (int*)(ws + 51465536);    // 1024
    int*   starts  = (int*)(ws + 51466560);    // 1025
    int*   cursor  = (int*)(ws + 51467585);    // 1024
    ushort* wp1_hi = (ushort*)(ws + 51468800); // 13*8*4*64*8 = 212992 ushorts
    ushort* wp1_lo = (ushort*)(ws + 51575296);
    ushort* wp0_hi = (ushort*)(ws + 51681792); // 7*8*5*64*8 = 143360 ushorts
    ushort* wp0_lo = (ushort*)(ws + 51753472);

    // weight conversion + bucketing (independent of conv pipeline)
    w1_convert_kernel<<<832, 256, 0, stream>>>(conv1_W, wp1_hi, wp1_lo);
    w0_convert_kernel<<<560, 256, 0, stream>>>(conv0_W, wp0_hi, wp0_lo);
    zero_counts_kernel<<<4, 256, 0, stream>>>(counts);
    hist_kernel<<<782, 256, 0, stream>>>(membership, counts);
    scan_kernel<<<1, 1024, 0, stream>>>(counts, starts, cursor);
    scatter_kernel<<<782, 256, 0, stream>>>(membership, cursor, idx);

    conv0_merged<<<3128, 256, 0, stream>>>(atom_features, wp0_hi, wp0_lo, conv0_b,
                                           bn0_g, bn0_b, adj, buf0);
    pool_merged<<<25001, 256, 0, stream>>>(buf0, adj, buf1);
    conv1_merged<<<3128, 256, 0, stream>>>(buf1, wp1_hi, wp1_lo, conv1_b,
                                           bn1_g, bn1_b, adj, buf0);
    dense0_pool_merged<<<3128, 256, 0, stream>>>(buf0, dense0_W, dense0_b,
                                                 bn2_g, bn2_b, adj, buf1);
    seg_dense1_kernel<<<1024, 256, 0, stream>>>(buf1, dense1_W, dense1_b,
                                                bn3_g, bn3_b, idx, starts, accum);
    final_kernel<<<256, 256, 0, stream>>>(accum, reg_W, reg_b, unc_W, unc_b, (float*)d_out);
}

// Round 9
// 548.425 us; speedup vs baseline: 1.0722x; 1.0722x over previous
//
#include <hip/hip_runtime.h>
#include <math.h>

// ---------------------------------------------------------------------------
// Static geometry: N_ATOMS=200000, MAX_DEG=6, NAF=75, BATCH=1024, N_TASKS=12
// DEG_COUNTS = [2000, 40000, 60000, 58000, 38000, 1500, 500]
// ---------------------------------------------------------------------------
constexpr int OFFS[8] = {0, 2000, 42000, 102000, 160000, 198000, 199500, 200000};
constexpr int CNT[7]  = {2000, 40000, 60000, 58000, 38000, 1500, 500};
// conv tiles (64 atoms): {32, 625, 938, 907, 594, 24, 8} cumsum:
constexpr int C_OFF[8] = {0, 32, 657, 1595, 2502, 3096, 3120, 3128};
// pool tiles (8 atoms): {250, 5000, 7500, 7250, 4750, 188, 63} cumsum:
constexpr int P_OFF[8] = {0, 250, 5250, 12750, 20000, 24750, 24938, 25001};
#define BN_SCALE_C 0.9999950000374997f  // 1/sqrt(1+1e-5)

struct Adjs { const int* a[6]; };

typedef __attribute__((ext_vector_type(8))) short bf16x8;
typedef __attribute__((ext_vector_type(4))) float f32x4;

// split fp32 -> bf16 hi (exact truncation) + bf16 lo (truncated remainder)
__device__ __forceinline__ void split1(float x, ushort& h, ushort& l) {
    const unsigned u = __float_as_uint(x);
    h = (ushort)(u >> 16);
    const float r = x - __uint_as_float(u & 0xffff0000u);
    l = (ushort)(__float_as_uint(r) >> 16);
}

// ---------------------------------------------------------------------------
// Weight conversion -> per-lane MFMA fragment layout:
//   Wfrag[s][g][ks][lane][i] ushort; col = g*16 + (lane&15),
//   k = ks*32 + (lane>>4)*8 + i. Every B load = coalesced 1KB dwordx4.
// conv1: s=0..12, K=128 (KS=4).  conv0: d=0..6, K=160 zero-padded (KS=5).
// ---------------------------------------------------------------------------
__global__ __launch_bounds__(256)
void w1_convert_kernel(const float* __restrict__ W, ushort* __restrict__ hi,
                       ushort* __restrict__ lo) {
    const int t = blockIdx.x * 256 + threadIdx.x;
    if (t >= 13 * 8 * 4 * 64 * 8) return;
    const int i = t & 7, l = (t >> 3) & 63, ks = (t >> 9) & 3,
              g = (t >> 11) & 7, s = t >> 14;
    const int col = g * 16 + (l & 15);
    const int k = ks * 32 + (l >> 4) * 8 + i;
    ushort h, lw;
    split1(W[(size_t)(s * 128 + k) * 128 + col], h, lw);
    hi[t] = h; lo[t] = lw;
}

__global__ __launch_bounds__(256)
void w0_convert_kernel(const float* __restrict__ W, ushort* __restrict__ hi,
                       ushort* __restrict__ lo) {
    const int t = blockIdx.x * 256 + threadIdx.x;
    if (t >= 7 * 8 * 5 * 64 * 8) return;
    const int i = t & 7;
    const int r = t >> 3;
    const int l = r & 63;
    const int r2 = r >> 6;
    const int ks = r2 % 5;
    const int r3 = r2 / 5;
    const int g = r3 & 7, d = r3 >> 3;
    const int col = g * 16 + (l & 15);
    const int k = ks * 32 + (l >> 4) * 8 + i;
    float v = 0.f;
    if (d == 0) {
        if (k < 75) v = W[(size_t)(12 * 75 + k) * 128 + col];
    } else {
        if (k < 75)       v = W[(size_t)((2 * d - 2) * 75 + k) * 128 + col];
        else if (k < 150) v = W[(size_t)((2 * d - 1) * 75 + (k - 75)) * 128 + col];
    }
    ushort h, lw;
    split1(v, h, lw);
    hi[t] = h; lo[t] = lw;
}

// ---------------------------------------------------------------------------
// MFMA GEMM core (R6-proven): block = 64 atoms x 128 cols, 4 waves; wave w
// owns atoms [16w,16w+16). acc[g] = 16x16 D tile for cols [16g,16g+16).
// A frags from LDS hi/lo bf16 planes; B frags = coalesced packed loads with
// depth-2 register rotation.
// ---------------------------------------------------------------------------
template<int KSTEPS, int SROW>
__device__ __forceinline__ void mfma_gemm(const ushort* sa_hi, const ushort* sa_lo,
                                          const ushort* wp_hi, const ushort* wp_lo,
                                          f32x4 acc[8], int l, int w)
{
    const int lr = l & 15, lq = l >> 4;
    const size_t lb = (size_t)l * 8;
    #pragma unroll
    for (int ks = 0; ks < KSTEPS; ++ks) {
        const int kb = ks * 32 + lq * 8;
        const bf16x8 ah = *(const bf16x8*)(sa_hi + (size_t)(w * 16 + lr) * SROW + kb);
        const bf16x8 al = *(const bf16x8*)(sa_lo + (size_t)(w * 16 + lr) * SROW + kb);
        bf16x8 bh0 = *(const bf16x8*)(wp_hi + (size_t)(0 * KSTEPS + ks) * 512 + lb);
        bf16x8 bl0 = *(const bf16x8*)(wp_lo + (size_t)(0 * KSTEPS + ks) * 512 + lb);
        bf16x8 bh1 = *(const bf16x8*)(wp_hi + (size_t)(1 * KSTEPS + ks) * 512 + lb);
        bf16x8 bl1 = *(const bf16x8*)(wp_lo + (size_t)(1 * KSTEPS + ks) * 512 + lb);
        #pragma unroll
        for (int g = 0; g < 8; ++g) {
            bf16x8 bh2 = bh0, bl2 = bl0;
            if (g < 6) {
                bh2 = *(const bf16x8*)(wp_hi + (size_t)((g + 2) * KSTEPS + ks) * 512 + lb);
                bl2 = *(const bf16x8*)(wp_lo + (size_t)((g + 2) * KSTEPS + ks) * 512 + lb);
            }
            acc[g] = __builtin_amdgcn_mfma_f32_16x16x32_bf16(ah, bh0, acc[g], 0, 0, 0);
            acc[g] = __builtin_amdgcn_mfma_f32_16x16x32_bf16(al, bh0, acc[g], 0, 0, 0);
            acc[g] = __builtin_amdgcn_mfma_f32_16x16x32_bf16(ah, bl0, acc[g], 0, 0, 0);
            bh0 = bh1; bl0 = bl1; bh1 = bh2; bl1 = bl2;
        }
    }
}

// ---------------------------------------------------------------------------
// Epilogue: acc -> LDS (fs[64][132] f32, re-using dead A planes) -> bias/relu/
// bn applied on coalesced float4 row writes (full 512B rows; no partial lines).
// D layout: col = g*16 + (lane&15), row = w*16 + (lane>>4)*4 + r  [m89]
// ---------------------------------------------------------------------------
__device__ __forceinline__ void mfma_epilogue(f32x4 acc[8], float* fs,
                                              const float* s_eb, float* out,
                                              int a0, int nat, int tid)
{
    const int l = tid & 63, w = tid >> 6, lr = l & 15, lq = l >> 4;
    __syncthreads();   // all waves done reading A planes
    #pragma unroll
    for (int g = 0; g < 8; ++g)
        #pragma unroll
        for (int r = 0; r < 4; ++r)
            fs[(size_t)(w * 16 + lq * 4 + r) * 132 + g * 16 + lr] = acc[g][r];
    __syncthreads();
    #pragma unroll
    for (int p = 0; p < 8; ++p) {
        const int row = p * 8 + (tid >> 5);
        if (row < nat) {
            const int c = (tid & 31) * 4;
            const float4 v  = *(const float4*)&fs[(size_t)row * 132 + c];
            const float4 bb = *(const float4*)&s_eb[c];
            const float4 gs = *(const float4*)&s_eb[128 + c];
            const float4 be = *(const float4*)&s_eb[256 + c];
            float4 o;
            o.x = fmaxf(v.x + bb.x, 0.f) * gs.x + be.x;
            o.y = fmaxf(v.y + bb.y, 0.f) * gs.y + be.y;
            o.z = fmaxf(v.z + bb.z, 0.f) * gs.z + be.z;
            o.w = fmaxf(v.w + bb.w, 0.f) * gs.w + be.w;
            *(float4*)(out + (size_t)(a0 + row) * 128 + c) = o;
        }
    }
}

// ---------------------------------------------------------------------------
// conv0 (MFMA): x[.][75] -> out[.][128]. A = [nbr-sum | self | 0pad], K=160.
// ---------------------------------------------------------------------------
template<int D>
__device__ __forceinline__ void conv0_body(int tile, const float* __restrict__ x,
    const ushort* __restrict__ wp_hi, const ushort* __restrict__ wp_lo,
    const float* __restrict__ b, const float* __restrict__ gamma,
    const float* __restrict__ beta, const int* __restrict__ adjp,
    float* __restrict__ out, ushort* s_ahi, ushort* s_alo, int* s_adj,
    float* s_eb, int tid)
{
    constexpr int SROW = 168;   // 160 + 8 pad (ushorts)
    const int a0 = OFFS[D] + tile * 64;
    const int nat = min(64, OFFS[D + 1] - a0);

    if (tid < 128) {
        float bb;
        if constexpr (D > 0)
            bb = b[(2 * D - 2) * 128 + tid] + b[(2 * D - 1) * 128 + tid];
        else
            bb = b[12 * 128 + tid];
        s_eb[tid] = bb;
        s_eb[128 + tid] = gamma[tid] * BN_SCALE_C;
        s_eb[256 + tid] = beta[tid];
    }
    if constexpr (D > 0) {
        for (int e = tid; e < 64 * D; e += 256) {
            const int al = e / D;
            if (al < nat)
                s_adj[e] = adjp[(size_t)(a0 - OFFS[D] + al) * D + (e - al * D)];
        }
        __syncthreads();
    }
    // zero the pad region (all 64 rows)
    if constexpr (D == 0) {
        for (int e = tid; e < 64 * 85; e += 256) {
            const int al = e / 85, k = 75 + e - (e / 85) * 85;
            s_ahi[al * SROW + k] = 0; s_alo[al * SROW + k] = 0;
        }
    } else {
        for (int e = tid; e < 64 * 10; e += 256) {
            const int al = e / 10, k = 150 + e - (e / 10) * 10;
            s_ahi[al * SROW + k] = 0; s_alo[al * SROW + k] = 0;
        }
    }
    // stage [nbr-sum | self]
    #pragma unroll 4
    for (int p = 0; p < 19; ++p) {
        const int e = p * 256 + tid;
        if (e < 4800) {
            const int al = e / 75;
            const int kk = e - al * 75;
            if (al < nat) {
                const float self = x[(size_t)(a0 + al) * 75 + kk];
                ushort h, l;
                if constexpr (D > 0) {
                    float sum = 0.f;
                    #pragma unroll
                    for (int i = 0; i < D; ++i)
                        sum += x[(size_t)s_adj[al * D + i] * 75 + kk];
                    split1(sum, h, l);
                    s_ahi[al * SROW + kk] = h; s_alo[al * SROW + kk] = l;
                    split1(self, h, l);
                    s_ahi[al * SROW + 75 + kk] = h; s_alo[al * SROW + 75 + kk] = l;
                } else {
                    split1(self, h, l);
                    s_ahi[al * SROW + kk] = h; s_alo[al * SROW + kk] = l;
                }
            }
        }
    }
    __syncthreads();

    const int l = tid & 63, w = tid >> 6;
    f32x4 acc[8];
    #pragma unroll
    for (int g = 0; g < 8; ++g) acc[g] = (f32x4){0.f, 0.f, 0.f, 0.f};
    mfma_gemm<5, SROW>(s_ahi, s_alo, wp_hi + (size_t)D * 20480,
                       wp_lo + (size_t)D * 20480, acc, l, w);
    mfma_epilogue(acc, (float*)s_ahi, s_eb, out, a0, nat, tid);
}

__global__ __launch_bounds__(256, 3)
void conv0_merged(const float* __restrict__ x, const ushort* __restrict__ wp_hi,
                  const ushort* __restrict__ wp_lo, const float* __restrict__ b,
                  const float* __restrict__ gamma, const float* __restrict__ beta,
                  Adjs adj, float* __restrict__ out)
{
    __shared__ ushort s_a[2][64 * 168];   // hi, lo; aliased as fs[64][132] f32
    __shared__ int s_adj[64 * 6];
    __shared__ float s_eb[384];
    const int blk = blockIdx.x, tid = threadIdx.x;
    #define C0(D) conv0_body<D>(blk - C_OFF[D], x, wp_hi, wp_lo, b, gamma, beta, \
        (D > 0) ? adj.a[D - 1] : nullptr, out, s_a[0], s_a[1], s_adj, s_eb, tid)
    if      (blk < C_OFF[1]) C0(0);
    else if (blk < C_OFF[2]) C0(1);
    else if (blk < C_OFF[3]) C0(2);
    else if (blk < C_OFF[4]) C0(3);
    else if (blk < C_OFF[5]) C0(4);
    else if (blk < C_OFF[6]) C0(5);
    else                     C0(6);
    #undef C0
}

// ---------------------------------------------------------------------------
// conv1 (MFMA): x[.][128] -> out[.][128].
// Phase0: neighbor-sum staged in LDS (self for D==0) -> GEMM vs W[2D-2].
// Phase1 (D>0): self rows read DIRECTLY from global in fragment layout,
// split in-register -> GEMM vs W[2D-1]. No second staging, no extra barriers.
// ---------------------------------------------------------------------------
template<int D>
__device__ __forceinline__ void conv1_stage0(const float* __restrict__ x,
    ushort* s_ahi, ushort* s_alo, const int* s_adj, int a0, int nat, int tid)
{
    constexpr int SROW = 136;
    #pragma unroll 2
    for (int p = 0; p < 8; ++p) {
        const int e = p * 256 + tid;
        const int al = e >> 5, c = e & 31;
        if (al < nat) {
            float4 v;
            if constexpr (D > 0) {
                v = make_float4(0.f, 0.f, 0.f, 0.f);
                #pragma unroll
                for (int i = 0; i < D; ++i) {
                    const float4 t = *((const float4*)(x + (size_t)s_adj[al * D + i] * 128) + c);
                    v.x += t.x; v.y += t.y; v.z += t.z; v.w += t.w;
                }
            } else {
                v = *((const float4*)(x + (size_t)(a0 + al) * 128) + c);
            }
            ushort4 h, lo;
            split1(v.x, h.x, lo.x); split1(v.y, h.y, lo.y);
            split1(v.z, h.z, lo.z); split1(v.w, h.w, lo.w);
            *(ushort4*)&s_ahi[al * SROW + c * 4] = h;
            *(ushort4*)&s_alo[al * SROW + c * 4] = lo;
        }
    }
}

// build bf16x8 hi/lo from two float4 (8 consecutive fp32)
__device__ __forceinline__ void split8(float4 s0, float4 s1, bf16x8& hv, bf16x8& lv)
{
    ushort h, l;
    split1(s0.x, h, l); hv[0] = (short)h; lv[0] = (short)l;
    split1(s0.y, h, l); hv[1] = (short)h; lv[1] = (short)l;
    split1(s0.z, h, l); hv[2] = (short)h; lv[2] = (short)l;
    split1(s0.w, h, l); hv[3] = (short)h; lv[3] = (short)l;
    split1(s1.x, h, l); hv[4] = (short)h; lv[4] = (short)l;
    split1(s1.y, h, l); hv[5] = (short)h; lv[5] = (short)l;
    split1(s1.z, h, l); hv[6] = (short)h; lv[6] = (short)l;
    split1(s1.w, h, l); hv[7] = (short)h; lv[7] = (short)l;
}

template<int D>
__device__ __forceinline__ void conv1_body(int tile, const float* __restrict__ x,
    const ushort* __restrict__ wp_hi, const ushort* __restrict__ wp_lo,
    const float* __restrict__ b, const float* __restrict__ gamma,
    const float* __restrict__ beta, const int* __restrict__ adjp,
    float* __restrict__ out, ushort* s_ahi, ushort* s_alo, int* s_adj,
    float* s_eb, int tid)
{
    constexpr int SROW = 136;
    const int a0 = OFFS[D] + tile * 64;
    const int nat = min(64, OFFS[D + 1] - a0);
    const int l = tid & 63, w = tid >> 6, lr = l & 15, lq = l >> 4;

    if (tid < 128) {
        float bb;
        if constexpr (D > 0)
            bb = b[(2 * D - 2) * 128 + tid] + b[(2 * D - 1) * 128 + tid];
        else
            bb = b[12 * 128 + tid];
        s_eb[tid] = bb;
        s_eb[128 + tid] = gamma[tid] * BN_SCALE_C;
        s_eb[256 + tid] = beta[tid];
    }
    if constexpr (D > 0) {
        for (int e = tid; e < 64 * D; e += 256) {
            const int al = e / D;
            if (al < nat)
                s_adj[e] = adjp[(size_t)(a0 - OFFS[D] + al) * D + (e - al * D)];
        }
        __syncthreads();
    }

    // --- issue self preload early (fragment layout, direct from global) ---
    float4 sv0, sv1, sv2, sv3, sv4, sv5, sv6, sv7;
    if constexpr (D > 0) {
        const int rowa = min(a0 + w * 16 + lr, 199999);
        const float* xr = x + (size_t)rowa * 128 + lq * 8;
        sv0 = *(const float4*)(xr +  0); sv1 = *(const float4*)(xr +  4);
        sv2 = *(const float4*)(xr + 32); sv3 = *(const float4*)(xr + 36);
        sv4 = *(const float4*)(xr + 64); sv5 = *(const float4*)(xr + 68);
        sv6 = *(const float4*)(xr + 96); sv7 = *(const float4*)(xr + 100);
    }

    f32x4 acc[8];
    #pragma unroll
    for (int g = 0; g < 8; ++g) acc[g] = (f32x4){0.f, 0.f, 0.f, 0.f};

    conv1_stage0<D>(x, s_ahi, s_alo, s_adj, a0, nat, tid);
    __syncthreads();
    {
        const size_t wb = (size_t)((D == 0) ? 12 : (2 * D - 2)) * 16384;
        mfma_gemm<4, SROW>(s_ahi, s_alo, wp_hi + wb, wp_lo + wb, acc, l, w);
    }

    if constexpr (D > 0) {
        // --- phase 1: self, A in-register ---
        const ushort* wh = wp_hi + (size_t)(2 * D - 1) * 16384;
        const ushort* wl = wp_lo + (size_t)(2 * D - 1) * 16384;
        const size_t lb = (size_t)l * 8;
        #pragma unroll
        for (int ks = 0; ks < 4; ++ks) {
            bf16x8 ah, al_;
            if      (ks == 0) split8(sv0, sv1, ah, al_);
            else if (ks == 1) split8(sv2, sv3, ah, al_);
            else if (ks == 2) split8(sv4, sv5, ah, al_);
            else              split8(sv6, sv7, ah, al_);
            bf16x8 bh0 = *(const bf16x8*)(wh + (size_t)(0 * 4 + ks) * 512 + lb);
            bf16x8 bl0 = *(const bf16x8*)(wl + (size_t)(0 * 4 + ks) * 512 + lb);
            bf16x8 bh1 = *(const bf16x8*)(wh + (size_t)(1 * 4 + ks) * 512 + lb);
            bf16x8 bl1 = *(const bf16x8*)(wl + (size_t)(1 * 4 + ks) * 512 + lb);
            #pragma unroll
            for (int g = 0; g < 8; ++g) {
                bf16x8 bh2 = bh0, bl2 = bl0;
                if (g < 6) {
                    bh2 = *(const bf16x8*)(wh + (size_t)((g + 2) * 4 + ks) * 512 + lb);
                    bl2 = *(const bf16x8*)(wl + (size_t)((g + 2) * 4 + ks) * 512 + lb);
                }
                acc[g] = __builtin_amdgcn_mfma_f32_16x16x32_bf16(ah, bh0, acc[g], 0, 0, 0);
                acc[g] = __builtin_amdgcn_mfma_f32_16x16x32_bf16(al_, bh0, acc[g], 0, 0, 0);
                acc[g] = __builtin_amdgcn_mfma_f32_16x16x32_bf16(ah, bl0, acc[g], 0, 0, 0);
                bh0 = bh1; bl0 = bl1; bh1 = bh2; bl1 = bl2;
            }
        }
    }
    mfma_epilogue(acc, (float*)s_ahi, s_eb, out, a0, nat, tid);
}

__global__ __launch_bounds__(256, 4)
void conv1_merged(const float* __restrict__ x, const ushort* __restrict__ wp_hi,
                  const ushort* __restrict__ wp_lo, const float* __restrict__ b,
                  const float* __restrict__ gamma, const float* __restrict__ beta,
                  Adjs adj, float* __restrict__ out)
{
    __shared__ ushort s_a[2][64 * 136];   // hi, lo; aliased as fs[64][132] f32
    __shared__ int s_adj[64 * 6];
    __shared__ float s_eb[384];
    const int blk = blockIdx.x, tid = threadIdx.x;
    #define C1(D) conv1_body<D>(blk - C_OFF[D], x, wp_hi, wp_lo, b, gamma, beta, \
        (D > 0) ? adj.a[D - 1] : nullptr, out, s_a[0], s_a[1], s_adj, s_eb, tid)
    if      (blk < C_OFF[1]) C1(0);
    else if (blk < C_OFF[2]) C1(1);
    else if (blk < C_OFF[3]) C1(2);
    else if (blk < C_OFF[4]) C1(3);
    else if (blk < C_OFF[5]) C1(4);
    else if (blk < C_OFF[6]) C1(5);
    else                     C1(6);
    #undef C1
}

// ---------------------------------------------------------------------------
// pool: out[a] = max(self, neighbors), 128 feats.
// ---------------------------------------------------------------------------
template<int D>
__device__ __forceinline__ void pool_body(int tile, const float* __restrict__ x,
    const int* __restrict__ adjp, float* __restrict__ out, int tid)
{
    const int tx = tid & 31;
    const int ai = tile * 8 + (tid >> 5);
    if (ai >= CNT[D]) return;
    const int a = OFFS[D] + ai;
    float4 v = *((const float4*)(x + (size_t)a * 128) + tx);
    if constexpr (D > 0) {
        #pragma unroll
        for (int i = 0; i < D; ++i) {
            const int n = adjp[(size_t)ai * D + i];
            const float4 t = *((const float4*)(x + (size_t)n * 128) + tx);
            v.x = fmaxf(v.x, t.x); v.y = fmaxf(v.y, t.y);
            v.z = fmaxf(v.z, t.z); v.w = fmaxf(v.w, t.w);
        }
    }
    *((float4*)(out + (size_t)a * 128) + tx) = v;
}

__global__ __launch_bounds__(256)
void pool_merged(const float* __restrict__ x, Adjs adj, float* __restrict__ out)
{
    const int blk = blockIdx.x, tid = threadIdx.x;
    #define PB(D) pool_body<D>(blk - P_OFF[D], x, (D > 0) ? adj.a[D - 1] : nullptr, out, tid)
    if      (blk < P_OFF[1]) PB(0);
    else if (blk < P_OFF[2]) PB(1);
    else if (blk < P_OFF[3]) PB(2);
    else if (blk < P_OFF[4]) PB(3);
    else if (blk < P_OFF[5]) PB(4);
    else if (blk < P_OFF[6]) PB(5);
    else                     PB(6);
    #undef PB
}

// ---------------------------------------------------------------------------
// dense0 with fused pool2, per-degree tiles: stage pooled rows in LDS,
// W[128][64] streamed from global (L1-resident) -> 4 blocks/CU.
// y = bn2(relu(pool(x) @ W + b)) -> out[200000][64]
// ---------------------------------------------------------------------------
template<int D>
__device__ __forceinline__ void d0_body(int tile, const float* __restrict__ x,
    const float* __restrict__ W, const float* __restrict__ b,
    const float* __restrict__ gamma, const float* __restrict__ beta,
    const int* __restrict__ adjp, float* __restrict__ out,
    float* s_a /*64*132*/, int* s_adj, int tid)
{
    const int a0 = OFFS[D] + tile * 64;
    const int nat = min(64, OFFS[D + 1] - a0);

    if constexpr (D > 0) {
        for (int e = tid; e < 64 * D; e += 256) {
            const int al = e / D;
            if (al < nat)
                s_adj[e] = adjp[(size_t)(a0 - OFFS[D] + al) * D + (e - al * D)];
        }
        __syncthreads();
    }
    {   // stage pooled rows: 8 atoms/pass, 32 lanes (float4) each
        const int tx4 = tid & 31, ag = tid >> 5;
        #pragma unroll
        for (int ap = 0; ap < 8; ++ap) {
            const int al = ap * 8 + ag;
            if (al < nat) {
                float4 v = *((const float4*)(x + (size_t)(a0 + al) * 128) + tx4);
                if constexpr (D > 0) {
                    #pragma unroll
                    for (int i = 0; i < D; ++i) {
                        const float4 t =
                            *((const float4*)(x + (size_t)s_adj[al * D + i] * 128) + tx4);
                        v.x = fmaxf(v.x, t.x); v.y = fmaxf(v.y, t.y);
                        v.z = fmaxf(v.z, t.z); v.w = fmaxf(v.w, t.w);
                    }
                }
                *(float4*)&s_a[al * 132 + tx4 * 4] = v;
            }
        }
    }
    __syncthreads();

    const int tx = tid & 15, ty = tid >> 4;
    float acc[4][4];
    #pragma unroll
    for (int i = 0; i < 4; ++i)
        #pragma unroll
        for (int j = 0; j < 4; ++j) acc[i][j] = 0.f;

    // K in steps of 4: float4 A reads (ds_read_b128), W from global (L1)
    #pragma unroll 4
    for (int k4 = 0; k4 < 32; ++k4) {
        float4 wk[4];
        #pragma unroll
        for (int kk = 0; kk < 4; ++kk)
            wk[kk] = *(const float4*)(W + (size_t)(k4 * 4 + kk) * 64 + tx * 4);
        #pragma unroll
        for (int i = 0; i < 4; ++i) {
            const float4 av = *(const float4*)&s_a[(ty * 4 + i) * 132 + k4 * 4];
            acc[i][0] = fmaf(av.x, wk[0].x, acc[i][0]);
            acc[i][1] = fmaf(av.x, wk[0].y, acc[i][1]);
            acc[i][2] = fmaf(av.x, wk[0].z, acc[i][2]);
            acc[i][3] = fmaf(av.x, wk[0].w, acc[i][3]);
            acc[i][0] = fmaf(av.y, wk[1].x, acc[i][0]);
            acc[i][1] = fmaf(av.y, wk[1].y, acc[i][1]);
            acc[i][2] = fmaf(av.y, wk[1].z, acc[i][2]);
            acc[i][3] = fmaf(av.y, wk[1].w, acc[i][3]);
            acc[i][0] = fmaf(av.z, wk[2].x, acc[i][0]);
            acc[i][1] = fmaf(av.z, wk[2].y, acc[i][1]);
            acc[i][2] = fmaf(av.z, wk[2].z, acc[i][2]);
            acc[i][3] = fmaf(av.z, wk[2].w, acc[i][3]);
            acc[i][0] = fmaf(av.w, wk[3].x, acc[i][0]);
            acc[i][1] = fmaf(av.w, wk[3].y, acc[i][1]);
            acc[i][2] = fmaf(av.w, wk[3].z, acc[i][2]);
            acc[i][3] = fmaf(av.w, wk[3].w, acc[i][3]);
        }
    }
    const int j = tx * 4;
    float bb[4], gs[4], be[4];
    #pragma unroll
    for (int c = 0; c < 4; ++c) {
        bb[c] = b[j + c]; gs[c] = gamma[j + c] * BN_SCALE_C; be[c] = beta[j + c];
    }
    #pragma unroll
    for (int i = 0; i < 4; ++i) {
        const int al = ty * 4 + i;
        if (al < nat) {
            float4 o;
            o.x = fmaxf(acc[i][0] + bb[0], 0.f) * gs[0] + be[0];
            o.y = fmaxf(acc[i][1] + bb[1], 0.f) * gs[1] + be[1];
            o.z = fmaxf(acc[i][2] + bb[2], 0.f) * gs[2] + be[2];
            o.w = fmaxf(acc[i][3] + bb[3], 0.f) * gs[3] + be[3];
            *(float4*)(out + (size_t)(a0 + al) * 64 + j) = o;
        }
    }
}

__global__ __launch_bounds__(256, 4)
void dense0_pool_merged(const float* __restrict__ x, const float* __restrict__ W,
                        const float* __restrict__ b, const float* __restrict__ gamma,
                        const float* __restrict__ beta, Adjs adj,
                        float* __restrict__ out)
{
    __shared__ float s_a[64 * 132];
    __shared__ int s_adj[64 * 6];
    const int blk = blockIdx.x, tid = threadIdx.x;
    #define D0(D) d0_body<D>(blk - C_OFF[D], x, W, b, gamma, beta, \
        (D > 0) ? adj.a[D - 1] : nullptr, out, s_a, s_adj, tid)
    if      (blk < C_OFF[1]) D0(0);
    else if (blk < C_OFF[2]) D0(1);
    else if (blk < C_OFF[3]) D0(2);
    else if (blk < C_OFF[4]) D0(3);
    else if (blk < C_OFF[5]) D0(4);
    else if (blk < C_OFF[6]) D0(5);
    else                     D0(6);
    #undef D0
}

// ---------------------------------------------------------------------------
// bucketing: counts -> scan -> scatter
// ---------------------------------------------------------------------------
__global__ void zero_counts_kernel(int* __restrict__ counts) {
    counts[blockIdx.x * 256 + threadIdx.x] = 0;   // grid 4
}

__global__ __launch_bounds__(256)
void hist_kernel(const int* __restrict__ mem, int* __restrict__ counts) {
    const int a = blockIdx.x * 256 + threadIdx.x;
    if (a < 200000) atomicAdd(&counts[mem[a]], 1);
}

__global__ __launch_bounds__(1024)
void scan_kernel(const int* __restrict__ counts, int* __restrict__ starts,
                 int* __restrict__ cursor) {
    __shared__ int s[1024];
    const int tid = threadIdx.x;
    s[tid] = counts[tid];
    __syncthreads();
    #pragma unroll
    for (int off = 1; off < 1024; off <<= 1) {
        const int v = (tid >= off) ? s[tid - off] : 0;
        __syncthreads();
        s[tid] += v;
        __syncthreads();
    }
    const int st = (tid == 0) ? 0 : s[tid - 1];
    starts[tid] = st;
    cursor[tid] = st;
    if (tid == 1023) starts[1024] = s[1023];
}

__global__ __launch_bounds__(256)
void scatter_kernel(const int* __restrict__ mem, int* __restrict__ cursor,
                    int* __restrict__ idx) {
    const int a = blockIdx.x * 256 + threadIdx.x;
    if (a < 200000) {
        const int p = atomicAdd(&cursor[mem[a]], 1);
        idx[p] = a;
    }
}

// ---------------------------------------------------------------------------
// per-segment fused dense1 + reduce: block = segment.
// ---------------------------------------------------------------------------
__global__ __launch_bounds__(256, 4)
void seg_dense1_kernel(const float* __restrict__ y0, const float* __restrict__ W,
                       const float* __restrict__ b, const float* __restrict__ gamma,
                       const float* __restrict__ beta, const int* __restrict__ idx,
                       const int* __restrict__ starts, float* __restrict__ accum)
{
    __shared__ float s_a[64][68];
    __shared__ float s_w[64][64];
    __shared__ float s_red[16][64];
    const int tid = threadIdx.x;
    const int seg = blockIdx.x;
    const int s0 = starts[seg];
    const int cnt = starts[seg + 1] - s0;

    #pragma unroll
    for (int p = 0; p < 4; ++p) {
        const int f = p * 256 + tid;
        const int r = f >> 4, c = (f & 15) * 4;
        *(float4*)&s_w[r][c] = *(const float4*)(W + r * 64 + c);
    }

    const int tx = tid & 15, ty = tid >> 4;
    const int j = tx * 4;
    float bb[4], gs[4], be[4];
    #pragma unroll
    for (int c = 0; c < 4; ++c) {
        bb[c] = b[j + c]; gs[c] = gamma[j + c] * BN_SCALE_C; be[c] = beta[j + c];
    }
    float facc[4] = {0.f, 0.f, 0.f, 0.f};

    for (int t0 = 0; t0 < cnt; t0 += 64) {
        const int nt = min(64, cnt - t0);
        __syncthreads();
        #pragma unroll
        for (int p = 0; p < 4; ++p) {
            const int e = p * 256 + tid;
            const int al = e >> 4, c = e & 15;
            if (al < nt) {
                const int a = idx[s0 + t0 + al];
                *(float4*)&s_a[al][c * 4] = *((const float4*)(y0 + (size_t)a * 64) + c);
            }
        }
        __syncthreads();
        float acc[4][4];
        #pragma unroll
        for (int i = 0; i < 4; ++i)
            #pragma unroll
            for (int c = 0; c < 4; ++c) acc[i][c] = 0.f;
        #pragma unroll 8
        for (int k = 0; k < 64; ++k) {
            const float4 w = *(float4*)&s_w[k][tx * 4];
            #pragma unroll
            for (int i = 0; i < 4; ++i) {
                const float av = s_a[ty * 4 + i][k];
                acc[i][0] = fmaf(av, w.x, acc[i][0]);
                acc[i][1] = fmaf(av, w.y, acc[i][1]);
                acc[i][2] = fmaf(av, w.z, acc[i][2]);
                acc[i][3] = fmaf(av, w.w, acc[i][3]);
            }
        }
        #pragma unroll
        for (int i = 0; i < 4; ++i) {
            if (ty * 4 + i < nt) {
                #pragma unroll
                for (int c = 0; c < 4; ++c)
                    facc[c] += fmaxf(acc[i][c] + bb[c], 0.f) * gs[c] + be[c];
            }
        }
    }
    __syncthreads();
    #pragma unroll
    for (int c = 0; c < 4; ++c) s_red[ty][j + c] = facc[c];
    __syncthreads();
    if (tid < 64) {
        float s = 0.f;
        #pragma unroll
        for (int q = 0; q < 16; ++q) s += s_red[q][tid];
        accum[(size_t)seg * 64 + tid] = s;
    }
}

// ---------------------------------------------------------------------------
// final: fp = tanh(accum); heads.
// d_out: out[12288] var[12288] out[12288] log_var[12288] fp[65536]
// ---------------------------------------------------------------------------
__global__ __launch_bounds__(256)
void final_kernel(const float* __restrict__ accum,
                  const float* __restrict__ regW, const float* __restrict__ regb,
                  const float* __restrict__ uncW, const float* __restrict__ uncb,
                  float* __restrict__ out)
{
    __shared__ float s_f[256];
    const int tid = threadIdx.x;
    const int rl = tid >> 6;
    const int c = tid & 63;
    const int r = blockIdx.x * 4 + rl;
    const float f = tanhf(accum[(size_t)r * 64 + c]);
    out[49152 + (size_t)r * 64 + c] = f;
    s_f[tid] = f;
    __syncthreads();
    if (c < 24) {
        const bool isreg = (c < 12);
        const int t = isreg ? c : c - 12;
        const float* Wm = isreg ? regW : uncW;
        float a = isreg ? regb[t] : uncb[t];
        #pragma unroll 8
        for (int k = 0; k < 64; ++k)
            a = fmaf(s_f[rl * 64 + k], Wm[k * 12 + t], a);
        if (isreg) {
            out[(size_t)r * 12 + t] = a;
            out[24576 + (size_t)r * 12 + t] = a;
        } else {
            out[36864 + (size_t)r * 12 + t] = a;
            out[12288 + (size_t)r * 12 + t] = expf(a);
        }
    }
}

// ---------------------------------------------------------------------------
extern "C" void kernel_launch(void* const* d_in, const int* in_sizes, int n_in,
                              void* d_out, int out_size, void* d_ws, size_t ws_size,
                              hipStream_t stream)
{
    const float* atom_features = (const float*)d_in[0];
    const int*   membership    = (const int*)d_in[2];
    Adjs adj;
    for (int d = 1; d <= 6; ++d) adj.a[d - 1] = (const int*)d_in[3 + d];
    const float* conv0_W = (const float*)d_in[10];
    const float* conv0_b = (const float*)d_in[11];
    const float* conv1_W = (const float*)d_in[12];
    const float* conv1_b = (const float*)d_in[13];
    const float* bn0_g = (const float*)d_in[14];
    const float* bn0_b = (const float*)d_in[15];
    const float* bn1_g = (const float*)d_in[16];
    const float* bn1_b = (const float*)d_in[17];
    const float* bn2_g = (const float*)d_in[18];
    const float* bn2_b = (const float*)d_in[19];
    const float* bn3_g = (const float*)d_in[20];
    const float* bn3_b = (const float*)d_in[21];
    const float* dense0_W = (const float*)d_in[22];
    const float* dense0_b = (const float*)d_in[23];
    const float* dense1_W = (const float*)d_in[24];
    const float* dense1_b = (const float*)d_in[25];
    const float* reg_W = (const float*)d_in[26];
    const float* reg_b = (const float*)d_in[27];
    const float* unc_W = (const float*)d_in[28];
    const float* unc_b = (const float*)d_in[29];

    float* ws    = (float*)d_ws;
    float* buf0  = ws;                         // 200000*128
    float* buf1  = ws + 25600000;              // 200000*128
    float* accum = ws + 51200000;              // 1024*64
    int*   idx     = (int*)(ws + 51265536);    // 200000
    int*   counts  = (int*)(ws + 51465536);    // 1024
    int*   starts  = (int*)(ws + 51466560);    // 1025
    int*   cursor  = (int*)(ws + 51467585);    // 1024
    ushort* wp1_hi = (ushort*)(ws + 51468800); // 13*8*4*64*8 = 212992 ushorts
    ushort* wp1_lo = (ushort*)(ws + 51575296);
    ushort* wp0_hi = (ushort*)(ws + 51681792); // 7*8*5*64*8 = 143360 ushorts
    ushort* wp0_lo = (ushort*)(ws + 51753472);

    // weight conversion + bucketing (independent of conv pipeline)
    w1_convert_kernel<<<832, 256, 0, stream>>>(conv1_W, wp1_hi, wp1_lo);
    w0_convert_kernel<<<560, 256, 0, stream>>>(conv0_W, wp0_hi, wp0_lo);
    zero_counts_kernel<<<4, 256, 0, stream>>>(counts);
    hist_kernel<<<782, 256, 0, stream>>>(membership, counts);
    scan_kernel<<<1, 1024, 0, stream>>>(counts, starts, cursor);
    scatter_kernel<<<782, 256, 0, stream>>>(membership, cursor, idx);

    conv0_merged<<<3128, 256, 0, stream>>>(atom_features, wp0_hi, wp0_lo, conv0_b,
                                           bn0_g, bn0_b, adj, buf0);
    pool_merged<<<25001, 256, 0, stream>>>(buf0, adj, buf1);
    conv1_merged<<<3128, 256, 0, stream>>>(buf1, wp1_hi, wp1_lo, conv1_b,
                                           bn1_g, bn1_b, adj, buf0);
    dense0_pool_merged<<<3128, 256, 0, stream>>>(buf0, dense0_W, dense0_b,
                                                 bn2_g, bn2_b, adj, buf1);
    seg_dense1_kernel<<<1024, 256, 0, stream>>>(buf1, dense1_W, dense1_b,
                                                bn3_g, bn3_b, idx, starts, accum);
    final_kernel<<<256, 256, 0, stream>>>(accum, reg_W, reg_b, unc_W, unc_b, (float*)d_out);
}

// Round 10
// 538.341 us; speedup vs baseline: 1.0923x; 1.0187x over previous
//
#include <hip/hip_runtime.h>
#include <math.h>

// ---------------------------------------------------------------------------
// Static geometry: N_ATOMS=200000, MAX_DEG=6, NAF=75, BATCH=1024, N_TASKS=12
// DEG_COUNTS = [2000, 40000, 60000, 58000, 38000, 1500, 500]
// ---------------------------------------------------------------------------
constexpr int OFFS[8] = {0, 2000, 42000, 102000, 160000, 198000, 199500, 200000};
constexpr int CNT[7]  = {2000, 40000, 60000, 58000, 38000, 1500, 500};
// conv tiles (64 atoms): {32, 625, 938, 907, 594, 24, 8} cumsum:
constexpr int C_OFF[8] = {0, 32, 657, 1595, 2502, 3096, 3120, 3128};
// pool tiles (8 atoms): {250, 5000, 7500, 7250, 4750, 188, 63} cumsum:
constexpr int P_OFF[8] = {0, 250, 5250, 12750, 20000, 24750, 24938, 25001};
#define BN_SCALE_C 0.9999950000374997f  // 1/sqrt(1+1e-5)

struct Adjs { const int* a[6]; };

typedef __attribute__((ext_vector_type(8))) short bf16x8;
typedef __attribute__((ext_vector_type(4))) float f32x4;

// split fp32 -> bf16 hi (exact truncation) + bf16 lo (truncated remainder)
__device__ __forceinline__ void split1(float x, ushort& h, ushort& l) {
    const unsigned u = __float_as_uint(x);
    h = (ushort)(u >> 16);
    const float r = x - __uint_as_float(u & 0xffff0000u);
    l = (ushort)(__float_as_uint(r) >> 16);
}

__device__ __forceinline__ void split8a(const float s[8], bf16x8& hv, bf16x8& lv) {
    #pragma unroll
    for (int i = 0; i < 8; ++i) {
        ushort h, lo;
        split1(s[i], h, lo);
        hv[i] = (short)h; lv[i] = (short)lo;
    }
}

// ---------------------------------------------------------------------------
// Weight conversion -> per-lane MFMA fragment layout:
//   Wfrag[m][g][ks][lane][i]; col = g*16 + (lane&15), k = ks*32 + (lane>>4)*8 + i.
// conv1: m=0..12, K=128 (KS=4).  conv0: m=0..12, K=96 zero-padded (KS=3).
// ---------------------------------------------------------------------------
__global__ __launch_bounds__(256)
void w1_convert_kernel(const float* __restrict__ W, ushort* __restrict__ hi,
                       ushort* __restrict__ lo) {
    const int t = blockIdx.x * 256 + threadIdx.x;
    if (t >= 13 * 8 * 4 * 64 * 8) return;
    const int i = t & 7, l = (t >> 3) & 63, ks = (t >> 9) & 3,
              g = (t >> 11) & 7, s = t >> 14;
    const int col = g * 16 + (l & 15);
    const int k = ks * 32 + (l >> 4) * 8 + i;
    ushort h, lw;
    split1(W[(size_t)(s * 128 + k) * 128 + col], h, lw);
    hi[t] = h; lo[t] = lw;
}

__global__ __launch_bounds__(256)
void w0_convert_kernel(const float* __restrict__ W, ushort* __restrict__ hi,
                       ushort* __restrict__ lo) {
    const int t = blockIdx.x * 256 + threadIdx.x;
    if (t >= 13 * 8 * 3 * 64 * 8) return;
    const int i = t & 7;
    const int l = (t >> 3) & 63;
    const int r2 = t >> 9;
    const int ks = r2 % 3;
    const int r3 = r2 / 3;
    const int g = r3 & 7, m = r3 >> 3;
    const int col = g * 16 + (l & 15);
    const int k = ks * 32 + (l >> 4) * 8 + i;
    float v = 0.f;
    if (k < 75) v = W[(size_t)(m * 75 + k) * 128 + col];
    ushort h, lw;
    split1(v, h, lw);
    hi[t] = h; lo[t] = lw;
}

// ---------------------------------------------------------------------------
// Per-lane row accumulate: s[i] += row[k0+i] (8 elems, bounds for ROWLEN=75)
// ---------------------------------------------------------------------------
template<int ROWLEN>
__device__ __forceinline__ void row_acc(const float* __restrict__ row, int k0,
                                        float s[8]) {
    if constexpr (ROWLEN == 128) {
        const float4 a = *(const float4*)(row + k0);
        const float4 b = *(const float4*)(row + k0 + 4);
        s[0] += a.x; s[1] += a.y; s[2] += a.z; s[3] += a.w;
        s[4] += b.x; s[5] += b.y; s[6] += b.z; s[7] += b.w;
    } else {
        #pragma unroll
        for (int i = 0; i < 8; ++i)
            if (k0 + i < ROWLEN) s[i] += row[k0 + i];
    }
}

// ---------------------------------------------------------------------------
// B-stream GEMM for one k-step: depth-2 register rotation over 8 col-groups.
// acc[g] = 16x16 D tile for cols [16g,16g+16).
// ---------------------------------------------------------------------------
template<int KS>
__device__ __forceinline__ void gemm_ks(const ushort* __restrict__ wh,
                                        const ushort* __restrict__ wl,
                                        int ks, size_t lb,
                                        bf16x8 ah, bf16x8 al_, f32x4 acc[8])
{
    bf16x8 bh0 = *(const bf16x8*)(wh + (size_t)(0 * KS + ks) * 512 + lb);
    bf16x8 bl0 = *(const bf16x8*)(wl + (size_t)(0 * KS + ks) * 512 + lb);
    bf16x8 bh1 = *(const bf16x8*)(wh + (size_t)(1 * KS + ks) * 512 + lb);
    bf16x8 bl1 = *(const bf16x8*)(wl + (size_t)(1 * KS + ks) * 512 + lb);
    #pragma unroll
    for (int g = 0; g < 8; ++g) {
        bf16x8 bh2 = bh0, bl2 = bl0;
        if (g < 6) {
            bh2 = *(const bf16x8*)(wh + (size_t)((g + 2) * KS + ks) * 512 + lb);
            bl2 = *(const bf16x8*)(wl + (size_t)((g + 2) * KS + ks) * 512 + lb);
        }
        acc[g] = __builtin_amdgcn_mfma_f32_16x16x32_bf16(ah, bh0, acc[g], 0, 0, 0);
        acc[g] = __builtin_amdgcn_mfma_f32_16x16x32_bf16(al_, bh0, acc[g], 0, 0, 0);
        acc[g] = __builtin_amdgcn_mfma_f32_16x16x32_bf16(ah, bl0, acc[g], 0, 0, 0);
        bh0 = bh1; bl0 = bl1; bh1 = bh2; bl1 = bl2;
    }
}

// ---------------------------------------------------------------------------
// Unified conv body (register-gathered A, LDS only for epilogue):
// block = 64 atoms x 128 cols, 4 waves; wave w owns atoms [16w,16w+16).
// Phase0: nbr-sum (self for D==0) vs W[m0]; Phase1 (D>0): self vs W[2D-1].
// Epilogue: half-tile LDS (fs[32][132]) -> coalesced full-row writes.
// D layout: col = g*16 + (lane&15), row = w*16 + (lane>>4)*4 + r  [m89]
// ---------------------------------------------------------------------------
template<int D, int ROWLEN, int KS>
__device__ __forceinline__ void conv_body(int tile, const float* __restrict__ x,
    const ushort* __restrict__ wp_hi, const ushort* __restrict__ wp_lo,
    const float* __restrict__ bias, const float* __restrict__ gamma,
    const float* __restrict__ beta, const int* __restrict__ adjp,
    float* __restrict__ out, float* fs, float* s_eb, int tid)
{
    const int a0 = OFFS[D] + tile * 64;
    const int nat = min(64, OFFS[D + 1] - a0);
    const int l = tid & 63, w = tid >> 6, lr = l & 15, lq = l >> 4;

    if (tid < 128) {
        float bb;
        if constexpr (D > 0)
            bb = bias[(2 * D - 2) * 128 + tid] + bias[(2 * D - 1) * 128 + tid];
        else
            bb = bias[12 * 128 + tid];
        s_eb[tid] = bb;
        s_eb[128 + tid] = gamma[tid] * BN_SCALE_C;
        s_eb[256 + tid] = beta[tid];
    }

    const int rowa = min(a0 + w * 16 + lr, OFFS[D + 1] - 1);
    int nb[(D > 0) ? D : 1];
    if constexpr (D > 0) {
        #pragma unroll
        for (int j = 0; j < D; ++j)
            nb[j] = adjp[(size_t)(rowa - OFFS[D]) * D + j];
    }

    f32x4 acc[8];
    #pragma unroll
    for (int g = 0; g < 8; ++g) acc[g] = (f32x4){0.f, 0.f, 0.f, 0.f};

    const size_t lb = (size_t)l * 8;

    // ---- phase 0: neighbor-sum (self for D==0) ----
    {
        const int m = (D == 0) ? 12 : (2 * D - 2);
        const ushort* wh = wp_hi + (size_t)m * (8 * KS * 512);
        const ushort* wl = wp_lo + (size_t)m * (8 * KS * 512);
        #pragma unroll
        for (int ks = 0; ks < KS; ++ks) {
            const int k0 = ks * 32 + lq * 8;
            float s[8] = {0.f, 0.f, 0.f, 0.f, 0.f, 0.f, 0.f, 0.f};
            if constexpr (D > 0) {
                #pragma unroll
                for (int j = 0; j < D; ++j)
                    row_acc<ROWLEN>(x + (size_t)nb[j] * ROWLEN, k0, s);
            } else {
                row_acc<ROWLEN>(x + (size_t)rowa * ROWLEN, k0, s);
            }
            bf16x8 ah, al_;
            split8a(s, ah, al_);
            gemm_ks<KS>(wh, wl, ks, lb, ah, al_, acc);
        }
    }
    // ---- phase 1 (D>0): self ----
    if constexpr (D > 0) {
        const ushort* wh = wp_hi + (size_t)(2 * D - 1) * (8 * KS * 512);
        const ushort* wl = wp_lo + (size_t)(2 * D - 1) * (8 * KS * 512);
        #pragma unroll
        for (int ks = 0; ks < KS; ++ks) {
            const int k0 = ks * 32 + lq * 8;
            float s[8] = {0.f, 0.f, 0.f, 0.f, 0.f, 0.f, 0.f, 0.f};
            row_acc<ROWLEN>(x + (size_t)rowa * ROWLEN, k0, s);
            bf16x8 ah, al_;
            split8a(s, ah, al_);
            gemm_ks<KS>(wh, wl, ks, lb, ah, al_, acc);
        }
    }

    // ---- epilogue: two half-tiles through fs[32][132] ----
    __syncthreads();   // s_eb visible
    #pragma unroll
    for (int h = 0; h < 2; ++h) {
        if ((w >> 1) == h) {
            const int wloc = w & 1;
            #pragma unroll
            for (int g = 0; g < 8; ++g)
                #pragma unroll
                for (int r = 0; r < 4; ++r)
                    fs[(wloc * 16 + lq * 4 + r) * 132 + g * 16 + lr] = acc[g][r];
        }
        __syncthreads();
        #pragma unroll
        for (int p = 0; p < 4; ++p) {
            const int fr = p * 8 + (tid >> 5);
            const int row = h * 32 + fr;
            if (row < nat) {
                const int c = (tid & 31) * 4;
                const float4 v  = *(const float4*)&fs[fr * 132 + c];
                const float4 bb = *(const float4*)&s_eb[c];
                const float4 gs = *(const float4*)&s_eb[128 + c];
                const float4 be = *(const float4*)&s_eb[256 + c];
                float4 o;
                o.x = fmaxf(v.x + bb.x, 0.f) * gs.x + be.x;
                o.y = fmaxf(v.y + bb.y, 0.f) * gs.y + be.y;
                o.z = fmaxf(v.z + bb.z, 0.f) * gs.z + be.z;
                o.w = fmaxf(v.w + bb.w, 0.f) * gs.w + be.w;
                *(float4*)(out + (size_t)(a0 + row) * 128 + c) = o;
            }
        }
        __syncthreads();
    }
}

__global__ __launch_bounds__(256, 4)
void conv0_merged(const float* __restrict__ x, const ushort* __restrict__ wp_hi,
                  const ushort* __restrict__ wp_lo, const float* __restrict__ b,
                  const float* __restrict__ gamma, const float* __restrict__ beta,
                  Adjs adj, float* __restrict__ out)
{
    __shared__ float fs[32 * 132];
    __shared__ float s_eb[384];
    const int blk = blockIdx.x, tid = threadIdx.x;
    #define C0(D) conv_body<D, 75, 3>(blk - C_OFF[D], x, wp_hi, wp_lo, b, gamma, \
        beta, (D > 0) ? adj.a[D - 1] : nullptr, out, fs, s_eb, tid)
    if      (blk < C_OFF[1]) C0(0);
    else if (blk < C_OFF[2]) C0(1);
    else if (blk < C_OFF[3]) C0(2);
    else if (blk < C_OFF[4]) C0(3);
    else if (blk < C_OFF[5]) C0(4);
    else if (blk < C_OFF[6]) C0(5);
    else                     C0(6);
    #undef C0
}

__global__ __launch_bounds__(256, 4)
void conv1_merged(const float* __restrict__ x, const ushort* __restrict__ wp_hi,
                  const ushort* __restrict__ wp_lo, const float* __restrict__ b,
                  const float* __restrict__ gamma, const float* __restrict__ beta,
                  Adjs adj, float* __restrict__ out)
{
    __shared__ float fs[32 * 132];
    __shared__ float s_eb[384];
    const int blk = blockIdx.x, tid = threadIdx.x;
    #define C1(D) conv_body<D, 128, 4>(blk - C_OFF[D], x, wp_hi, wp_lo, b, gamma, \
        beta, (D > 0) ? adj.a[D - 1] : nullptr, out, fs, s_eb, tid)
    if      (blk < C_OFF[1]) C1(0);
    else if (blk < C_OFF[2]) C1(1);
    else if (blk < C_OFF[3]) C1(2);
    else if (blk < C_OFF[4]) C1(3);
    else if (blk < C_OFF[5]) C1(4);
    else if (blk < C_OFF[6]) C1(5);
    else                     C1(6);
    #undef C1
}

// ---------------------------------------------------------------------------
// pool: out[a] = max(self, neighbors), 128 feats.
// ---------------------------------------------------------------------------
template<int D>
__device__ __forceinline__ void pool_body(int tile, const float* __restrict__ x,
    const int* __restrict__ adjp, float* __restrict__ out, int tid)
{
    const int tx = tid & 31;
    const int ai = tile * 8 + (tid >> 5);
    if (ai >= CNT[D]) return;
    const int a = OFFS[D] + ai;
    float4 v = *((const float4*)(x + (size_t)a * 128) + tx);
    if constexpr (D > 0) {
        #pragma unroll
        for (int i = 0; i < D; ++i) {
            const int n = adjp[(size_t)ai * D + i];
            const float4 t = *((const float4*)(x + (size_t)n * 128) + tx);
            v.x = fmaxf(v.x, t.x); v.y = fmaxf(v.y, t.y);
            v.z = fmaxf(v.z, t.z); v.w = fmaxf(v.w, t.w);
        }
    }
    *((float4*)(out + (size_t)a * 128) + tx) = v;
}

__global__ __launch_bounds__(256)
void pool_merged(const float* __restrict__ x, Adjs adj, float* __restrict__ out)
{
    const int blk = blockIdx.x, tid = threadIdx.x;
    #define PB(D) pool_body<D>(blk - P_OFF[D], x, (D > 0) ? adj.a[D - 1] : nullptr, out, tid)
    if      (blk < P_OFF[1]) PB(0);
    else if (blk < P_OFF[2]) PB(1);
    else if (blk < P_OFF[3]) PB(2);
    else if (blk < P_OFF[4]) PB(3);
    else if (blk < P_OFF[5]) PB(4);
    else if (blk < P_OFF[6]) PB(5);
    else                     PB(6);
    #undef PB
}

// ---------------------------------------------------------------------------
// dense0 with fused pool2, per-degree tiles: stage pooled rows in LDS,
// W[128][64] streamed from global (L1-resident).
// ---------------------------------------------------------------------------
template<int D>
__device__ __forceinline__ void d0_body(int tile, const float* __restrict__ x,
    const float* __restrict__ W, const float* __restrict__ b,
    const float* __restrict__ gamma, const float* __restrict__ beta,
    const int* __restrict__ adjp, float* __restrict__ out,
    float* s_a /*64*132*/, int* s_adj, int tid)
{
    const int a0 = OFFS[D] + tile * 64;
    const int nat = min(64, OFFS[D + 1] - a0);

    if constexpr (D > 0) {
        for (int e = tid; e < 64 * D; e += 256) {
            const int al = e / D;
            if (al < nat)
                s_adj[e] = adjp[(size_t)(a0 - OFFS[D] + al) * D + (e - al * D)];
        }
        __syncthreads();
    }
    {
        const int tx4 = tid & 31, ag = tid >> 5;
        #pragma unroll
        for (int ap = 0; ap < 8; ++ap) {
            const int al = ap * 8 + ag;
            if (al < nat) {
                float4 v = *((const float4*)(x + (size_t)(a0 + al) * 128) + tx4);
                if constexpr (D > 0) {
                    #pragma unroll
                    for (int i = 0; i < D; ++i) {
                        const float4 t =
                            *((const float4*)(x + (size_t)s_adj[al * D + i] * 128) + tx4);
                        v.x = fmaxf(v.x, t.x); v.y = fmaxf(v.y, t.y);
                        v.z = fmaxf(v.z, t.z); v.w = fmaxf(v.w, t.w);
                    }
                }
                *(float4*)&s_a[al * 132 + tx4 * 4] = v;
            }
        }
    }
    __syncthreads();

    const int tx = tid & 15, ty = tid >> 4;
    float acc[4][4];
    #pragma unroll
    for (int i = 0; i < 4; ++i)
        #pragma unroll
        for (int j = 0; j < 4; ++j) acc[i][j] = 0.f;

    #pragma unroll 4
    for (int k4 = 0; k4 < 32; ++k4) {
        float4 wk[4];
        #pragma unroll
        for (int kk = 0; kk < 4; ++kk)
            wk[kk] = *(const float4*)(W + (size_t)(k4 * 4 + kk) * 64 + tx * 4);
        #pragma unroll
        for (int i = 0; i < 4; ++i) {
            const float4 av = *(const float4*)&s_a[(ty * 4 + i) * 132 + k4 * 4];
            acc[i][0] = fmaf(av.x, wk[0].x, acc[i][0]);
            acc[i][1] = fmaf(av.x, wk[0].y, acc[i][1]);
            acc[i][2] = fmaf(av.x, wk[0].z, acc[i][2]);
            acc[i][3] = fmaf(av.x, wk[0].w, acc[i][3]);
            acc[i][0] = fmaf(av.y, wk[1].x, acc[i][0]);
            acc[i][1] = fmaf(av.y, wk[1].y, acc[i][1]);
            acc[i][2] = fmaf(av.y, wk[1].z, acc[i][2]);
            acc[i][3] = fmaf(av.y, wk[1].w, acc[i][3]);
            acc[i][0] = fmaf(av.z, wk[2].x, acc[i][0]);
            acc[i][1] = fmaf(av.z, wk[2].y, acc[i][1]);
            acc[i][2] = fmaf(av.z, wk[2].z, acc[i][2]);
            acc[i][3] = fmaf(av.z, wk[2].w, acc[i][3]);
            acc[i][0] = fmaf(av.w, wk[3].x, acc[i][0]);
            acc[i][1] = fmaf(av.w, wk[3].y, acc[i][1]);
            acc[i][2] = fmaf(av.w, wk[3].z, acc[i][2]);
            acc[i][3] = fmaf(av.w, wk[3].w, acc[i][3]);
        }
    }
    const int j = tx * 4;
    float bb[4], gs[4], be[4];
    #pragma unroll
    for (int c = 0; c < 4; ++c) {
        bb[c] = b[j + c]; gs[c] = gamma[j + c] * BN_SCALE_C; be[c] = beta[j + c];
    }
    #pragma unroll
    for (int i = 0; i < 4; ++i) {
        const int al = ty * 4 + i;
        if (al < nat) {
            float4 o;
            o.x = fmaxf(acc[i][0] + bb[0], 0.f) * gs[0] + be[0];
            o.y = fmaxf(acc[i][1] + bb[1], 0.f) * gs[1] + be[1];
            o.z = fmaxf(acc[i][2] + bb[2], 0.f) * gs[2] + be[2];
            o.w = fmaxf(acc[i][3] + bb[3], 0.f) * gs[3] + be[3];
            *(float4*)(out + (size_t)(a0 + al) * 64 + j) = o;
        }
    }
}

__global__ __launch_bounds__(256, 4)
void dense0_pool_merged(const float* __restrict__ x, const float* __restrict__ W,
                        const float* __restrict__ b, const float* __restrict__ gamma,
                        const float* __restrict__ beta, Adjs adj,
                        float* __restrict__ out)
{
    __shared__ float s_a[64 * 132];
    __shared__ int s_adj[64 * 6];
    const int blk = blockIdx.x, tid = threadIdx.x;
    #define D0(D) d0_body<D>(blk - C_OFF[D], x, W, b, gamma, beta, \
        (D > 0) ? adj.a[D - 1] : nullptr, out, s_a, s_adj, tid)
    if      (blk < C_OFF[1]) D0(0);
    else if (blk < C_OFF[2]) D0(1);
    else if (blk < C_OFF[3]) D0(2);
    else if (blk < C_OFF[4]) D0(3);
    else if (blk < C_OFF[5]) D0(4);
    else if (blk < C_OFF[6]) D0(5);
    else                     D0(6);
    #undef D0
}

// ---------------------------------------------------------------------------
// bucketing: counts -> scan -> scatter
// ---------------------------------------------------------------------------
__global__ void zero_counts_kernel(int* __restrict__ counts) {
    counts[blockIdx.x * 256 + threadIdx.x] = 0;   // grid 4
}

__global__ __launch_bounds__(256)
void hist_kernel(const int* __restrict__ mem, int* __restrict__ counts) {
    const int a = blockIdx.x * 256 + threadIdx.x;
    if (a < 200000) atomicAdd(&counts[mem[a]], 1);
}

__global__ __launch_bounds__(1024)
void scan_kernel(const int* __restrict__ counts, int* __restrict__ starts,
                 int* __restrict__ cursor) {
    __shared__ int s[1024];
    const int tid = threadIdx.x;
    s[tid] = counts[tid];
    __syncthreads();
    #pragma unroll
    for (int off = 1; off < 1024; off <<= 1) {
        const int v = (tid >= off) ? s[tid - off] : 0;
        __syncthreads();
        s[tid] += v;
        __syncthreads();
    }
    const int st = (tid == 0) ? 0 : s[tid - 1];
    starts[tid] = st;
    cursor[tid] = st;
    if (tid == 1023) starts[1024] = s[1023];
}

__global__ __launch_bounds__(256)
void scatter_kernel(const int* __restrict__ mem, int* __restrict__ cursor,
                    int* __restrict__ idx) {
    const int a = blockIdx.x * 256 + threadIdx.x;
    if (a < 200000) {
        const int p = atomicAdd(&cursor[mem[a]], 1);
        idx[p] = a;
    }
}

// ---------------------------------------------------------------------------
// per-segment fused dense1 + reduce: block = segment.
// ---------------------------------------------------------------------------
__global__ __launch_bounds__(256, 4)
void seg_dense1_kernel(const float* __restrict__ y0, const float* __restrict__ W,
                       const float* __restrict__ b, const float* __restrict__ gamma,
                       const float* __restrict__ beta, const int* __restrict__ idx,
                       const int* __restrict__ starts, float* __restrict__ accum)
{
    __shared__ float s_a[64][68];
    __shared__ float s_w[64][64];
    __shared__ float s_red[16][64];
    const int tid = threadIdx.x;
    const int seg = blockIdx.x;
    const int s0 = starts[seg];
    const int cnt = starts[seg + 1] - s0;

    #pragma unroll
    for (int p = 0; p < 4; ++p) {
        const int f = p * 256 + tid;
        const int r = f >> 4, c = (f & 15) * 4;
        *(float4*)&s_w[r][c] = *(const float4*)(W + r * 64 + c);
    }

    const int tx = tid & 15, ty = tid >> 4;
    const int j = tx * 4;
    float bb[4], gs[4], be[4];
    #pragma unroll
    for (int c = 0; c < 4; ++c) {
        bb[c] = b[j + c]; gs[c] = gamma[j + c] * BN_SCALE_C; be[c] = beta[j + c];
    }
    float facc[4] = {0.f, 0.f, 0.f, 0.f};

    for (int t0 = 0; t0 < cnt; t0 += 64) {
        const int nt = min(64, cnt - t0);
        __syncthreads();
        #pragma unroll
        for (int p = 0; p < 4; ++p) {
            const int e = p * 256 + tid;
            const int al = e >> 4, c = e & 15;
            if (al < nt) {
                const int a = idx[s0 + t0 + al];
                *(float4*)&s_a[al][c * 4] = *((const float4*)(y0 + (size_t)a * 64) + c);
            }
        }
        __syncthreads();
        float acc[4][4];
        #pragma unroll
        for (int i = 0; i < 4; ++i)
            #pragma unroll
            for (int c = 0; c < 4; ++c) acc[i][c] = 0.f;
        #pragma unroll 8
        for (int k = 0; k < 64; ++k) {
            const float4 w = *(float4*)&s_w[k][tx * 4];
            #pragma unroll
            for (int i = 0; i < 4; ++i) {
                const float av = s_a[ty * 4 + i][k];
                acc[i][0] = fmaf(av, w.x, acc[i][0]);
                acc[i][1] = fmaf(av, w.y, acc[i][1]);
                acc[i][2] = fmaf(av, w.z, acc[i][2]);
                acc[i][3] = fmaf(av, w.w, acc[i][3]);
            }
        }
        #pragma unroll
        for (int i = 0; i < 4; ++i) {
            if (ty * 4 + i < nt) {
                #pragma unroll
                for (int c = 0; c < 4; ++c)
                    facc[c] += fmaxf(acc[i][c] + bb[c], 0.f) * gs[c] + be[c];
            }
        }
    }
    __syncthreads();
    #pragma unroll
    for (int c = 0; c < 4; ++c) s_red[ty][j + c] = facc[c];
    __syncthreads();
    if (tid < 64) {
        float s = 0.f;
        #pragma unroll
        for (int q = 0; q < 16; ++q) s += s_red[q][tid];
        accum[(size_t)seg * 64 + tid] = s;
    }
}

// ---------------------------------------------------------------------------
// final: fp = tanh(accum); heads.
// d_out: out[12288] var[12288] out[12288] log_var[12288] fp[65536]
// ---------------------------------------------------------------------------
__global__ __launch_bounds__(256)
void final_kernel(const float* __restrict__ accum,
                  const float* __restrict__ regW, const float* __restrict__ regb,
                  const float* __restrict__ uncW, const float* __restrict__ uncb,
                  float* __restrict__ out)
{
    __shared__ float s_f[256];
    const int tid = threadIdx.x;
    const int rl = tid >> 6;
    const int c = tid & 63;
    const int r = blockIdx.x * 4 + rl;
    const float f = tanhf(accum[(size_t)r * 64 + c]);
    out[49152 + (size_t)r * 64 + c] = f;
    s_f[tid] = f;
    __syncthreads();
    if (c < 24) {
        const bool isreg = (c < 12);
        const int t = isreg ? c : c - 12;
        const float* Wm = isreg ? regW : uncW;
        float a = isreg ? regb[t] : uncb[t];
        #pragma unroll 8
        for (int k = 0; k < 64; ++k)
            a = fmaf(s_f[rl * 64 + k], Wm[k * 12 + t], a);
        if (isreg) {
            out[(size_t)r * 12 + t] = a;
            out[24576 + (size_t)r * 12 + t] = a;
        } else {
            out[36864 + (size_t)r * 12 + t] = a;
            out[12288 + (size_t)r * 12 + t] = expf(a);
        }
    }
}

// ---------------------------------------------------------------------------
extern "C" void kernel_launch(void* const* d_in, const int* in_sizes, int n_in,
                              void* d_out, int out_size, void* d_ws, size_t ws_size,
                              hipStream_t stream)
{
    const float* atom_features = (const float*)d_in[0];
    const int*   membership    = (const int*)d_in[2];
    Adjs adj;
    for (int d = 1; d <= 6; ++d) adj.a[d - 1] = (const int*)d_in[3 + d];
    const float* conv0_W = (const float*)d_in[10];
    const float* conv0_b = (const float*)d_in[11];
    const float* conv1_W = (const float*)d_in[12];
    const float* conv1_b = (const float*)d_in[13];
    const float* bn0_g = (const float*)d_in[14];
    const float* bn0_b = (const float*)d_in[15];
    const float* bn1_g = (const float*)d_in[16];
    const float* bn1_b = (const float*)d_in[17];
    const float* bn2_g = (const float*)d_in[18];
    const float* bn2_b = (const float*)d_in[19];
    const float* bn3_g = (const float*)d_in[20];
    const float* bn3_b = (const float*)d_in[21];
    const float* dense0_W = (const float*)d_in[22];
    const float* dense0_b = (const float*)d_in[23];
    const float* dense1_W = (const float*)d_in[24];
    const float* dense1_b = (const float*)d_in[25];
    const float* reg_W = (const float*)d_in[26];
    const float* reg_b = (const float*)d_in[27];
    const float* unc_W = (const float*)d_in[28];
    const float* unc_b = (const float*)d_in[29];

    float* ws    = (float*)d_ws;
    float* buf0  = ws;                         // 200000*128
    float* buf1  = ws + 25600000;              // 200000*128
    float* accum = ws + 51200000;              // 1024*64
    int*   idx     = (int*)(ws + 51265536);    // 200000
    int*   counts  = (int*)(ws + 51465536);    // 1024
    int*   starts  = (int*)(ws + 51466560);    // 1025
    int*   cursor  = (int*)(ws + 51467585);    // 1024
    ushort* wp1_hi = (ushort*)(ws + 51468800); // 13*8*4*512 = 212992 ushorts
    ushort* wp1_lo = (ushort*)(ws + 51575296);
    ushort* wp0_hi = (ushort*)(ws + 51681792); // 13*8*3*512 = 159744 ushorts
    ushort* wp0_lo = (ushort*)(ws + 51761664);

    // weight conversion + bucketing (independent of conv pipeline)
    w1_convert_kernel<<<832, 256, 0, stream>>>(conv1_W, wp1_hi, wp1_lo);
    w0_convert_kernel<<<624, 256, 0, stream>>>(conv0_W, wp0_hi, wp0_lo);
    zero_counts_kernel<<<4, 256, 0, stream>>>(counts);
    hist_kernel<<<782, 256, 0, stream>>>(membership, counts);
    scan_kernel<<<1, 1024, 0, stream>>>(counts, starts, cursor);
    scatter_kernel<<<782, 256, 0, stream>>>(membership, cursor, idx);

    conv0_merged<<<3128, 256, 0, stream>>>(atom_features, wp0_hi, wp0_lo, conv0_b,
                                           bn0_g, bn0_b, adj, buf0);
    pool_merged<<<25001, 256, 0, stream>>>(buf0, adj, buf1);
    conv1_merged<<<3128, 256, 0, stream>>>(buf1, wp1_hi, wp1_lo, conv1_b,
                                           bn1_g, bn1_b, adj, buf0);
    dense0_pool_merged<<<3128, 256, 0, stream>>>(buf0, dense0_W, dense0_b,
                                                 bn2_g, bn2_b, adj, buf1);
    seg_dense1_kernel<<<1024, 256, 0, stream>>>(buf1, dense1_W, dense1_b,
                                                bn3_g, bn3_b, idx, starts, accum);
    final_kernel<<<256, 256, 0, stream>>>(accum, reg_W, reg_b, unc_W, unc_b, (float*)d_out);
}